// Round 2
// baseline (797.160 us; speedup 1.0000x reference)
//
#include <hip/hip_runtime.h>
#include <math.h>

typedef __attribute__((ext_vector_type(8))) __bf16 bf16x8;
typedef __attribute__((ext_vector_type(4))) __bf16 bf16x4;
typedef __attribute__((ext_vector_type(4))) float f32x4;

// max over the 16-lane group via DPP row rotations (VALU, not LDS pipe)
__device__ __forceinline__ float rowmax16(float x) {
    int xi = __builtin_bit_cast(int, x);
    float y;
    y = __builtin_bit_cast(float, __builtin_amdgcn_update_dpp(0, xi, 0x128, 0xf, 0xf, true)); // ror:8
    x = fmaxf(x, y); xi = __builtin_bit_cast(int, x);
    y = __builtin_bit_cast(float, __builtin_amdgcn_update_dpp(0, xi, 0x124, 0xf, 0xf, true)); // ror:4
    x = fmaxf(x, y); xi = __builtin_bit_cast(int, x);
    y = __builtin_bit_cast(float, __builtin_amdgcn_update_dpp(0, xi, 0x122, 0xf, 0xf, true)); // ror:2
    x = fmaxf(x, y); xi = __builtin_bit_cast(int, x);
    y = __builtin_bit_cast(float, __builtin_amdgcn_update_dpp(0, xi, 0x121, 0xf, 0xf, true)); // ror:1
    x = fmaxf(x, y);
    return x;
}

// ---------------------------------------------------------------------------
// prep: transpose + bf16-cast the three epilogue weight matrices.
// ---------------------------------------------------------------------------
__global__ void prep_kernel(const float* __restrict__ wlin,
                            const float* __restrict__ wu2,
                            const float* __restrict__ wsc,
                            __bf16* __restrict__ wlinT,
                            __bf16* __restrict__ wu2T,
                            __bf16* __restrict__ wscT)
{
    int i = blockIdx.x * 256 + threadIdx.x;
    if (i < 64 * 512) {
        int l = i >> 9, k = i & 511;
        wlinT[i] = (__bf16)wlin[k * 64 + l];
    } else if (i < 64 * 512 + 128 * 64) {
        int j = i - 64 * 512; int co = j >> 6, kk = j & 63;
        wu2T[j] = (__bf16)wu2[kk * 128 + co];
    } else if (i < 64 * 512 + 2 * 128 * 64) {
        int j = i - 64 * 512 - 128 * 64; int co = j >> 6, kk = j & 63;
        wscT[j] = (__bf16)wsc[kk * 128 + co];
    }
}

// ---------------------------------------------------------------------------
// Kernel A v3: tiled LDS GEMM, 128 points/block, thread = 4x4 sub-tile.
// acc lives in 16 VGPRs (v2's in[64]/acc[32] likely spilled to scratch).
// Also emits dfb (bf16 dense_feats, exact for maxpool: max commutes with
// monotone rounding) and gxb (bf16 guidance) to halve pcf's gather streams.
// ---------------------------------------------------------------------------
__global__ __launch_bounds__(256) void feats_kernel(
    const float* __restrict__ df,
    const float* __restrict__ w1, const float* __restrict__ b1,
    const float* __restrict__ wg, const float* __restrict__ bg,
    float* __restrict__ fx, __bf16* __restrict__ gxb,
    __bf16* __restrict__ dfb, int N)
{
    __shared__ float sA[64][132];    // input tile transposed: sA[k][p]
    __shared__ float sW1[64][32];
    __shared__ float sWg[32][32];
    __shared__ float sFxT[32][132];  // fx tile transposed for GEMM2
    int t = threadIdx.x;
    for (int i = t; i < 64 * 32; i += 256) ((float*)sW1)[i] = w1[i];
    for (int i = t; i < 32 * 32; i += 256) ((float*)sWg)[i] = wg[i];
    long p0 = (long)blockIdx.x * 128;

    // stage tile (coalesced: 16 lanes = one 256B row), transpose into LDS,
    // and emit bf16 copy of df.
#pragma unroll
    for (int it = 0; it < 8; ++it) {
        int idx = it * 256 + t;
        int pl = idx >> 4, k4 = (idx & 15) * 4;
        long n = p0 + pl;
        float4 a = make_float4(0.f, 0.f, 0.f, 0.f);
        if (n < N) a = *(const float4*)(df + n * 64 + k4);
        sA[k4 + 0][pl] = a.x; sA[k4 + 1][pl] = a.y;
        sA[k4 + 2][pl] = a.z; sA[k4 + 3][pl] = a.w;
        if (n < N) {
            bf16x4 pk;
            pk[0] = (__bf16)a.x; pk[1] = (__bf16)a.y;
            pk[2] = (__bf16)a.z; pk[3] = (__bf16)a.w;
            *(bf16x4*)(dfb + n * 64 + k4) = pk;
        }
    }
    __syncthreads();

    int tp = t & 31, tc = t >> 5;    // 32 p-groups x 8 c-groups
    // GEMM1: fx = leaky(df @ w1 + b1)
    float acc[4][4];
#pragma unroll
    for (int pp = 0; pp < 4; pp++)
#pragma unroll
        for (int cc = 0; cc < 4; cc++) acc[pp][cc] = b1[tc * 4 + cc];
#pragma unroll
    for (int k = 0; k < 64; k++) {
        float4 av = *(const float4*)(&sA[k][tp * 4]);
        float4 bv = *(const float4*)(&sW1[k][tc * 4]);
        float aa[4] = {av.x, av.y, av.z, av.w};
        float bb[4] = {bv.x, bv.y, bv.z, bv.w};
#pragma unroll
        for (int pp = 0; pp < 4; pp++)
#pragma unroll
            for (int cc = 0; cc < 4; cc++) acc[pp][cc] += aa[pp] * bb[cc];
    }
#pragma unroll
    for (int pp = 0; pp < 4; pp++)
#pragma unroll
        for (int cc = 0; cc < 4; cc++) {
            float x = acc[pp][cc];
            acc[pp][cc] = x > 0.f ? x : 0.1f * x;
        }
#pragma unroll
    for (int pp = 0; pp < 4; pp++) {
        long n = p0 + tp * 4 + pp;
        if (n < N)
            *(float4*)(fx + n * 32 + tc * 4) =
                make_float4(acc[pp][0], acc[pp][1], acc[pp][2], acc[pp][3]);
#pragma unroll
        for (int cc = 0; cc < 4; cc++) sFxT[tc * 4 + cc][tp * 4 + pp] = acc[pp][cc];
    }
    __syncthreads();

    // GEMM2: gx = fx @ wg + bg  (stored bf16)
    float acc2[4][4];
#pragma unroll
    for (int pp = 0; pp < 4; pp++)
#pragma unroll
        for (int cc = 0; cc < 4; cc++) acc2[pp][cc] = bg[tc * 4 + cc];
#pragma unroll
    for (int k = 0; k < 32; k++) {
        float4 av = *(const float4*)(&sFxT[k][tp * 4]);
        float4 bv = *(const float4*)(&sWg[k][tc * 4]);
        float aa[4] = {av.x, av.y, av.z, av.w};
        float bb[4] = {bv.x, bv.y, bv.z, bv.w};
#pragma unroll
        for (int pp = 0; pp < 4; pp++)
#pragma unroll
            for (int cc = 0; cc < 4; cc++) acc2[pp][cc] += aa[pp] * bb[cc];
    }
#pragma unroll
    for (int pp = 0; pp < 4; pp++) {
        long n = p0 + tp * 4 + pp;
        if (n < N) {
            bf16x4 pk;
#pragma unroll
            for (int cc = 0; cc < 4; cc++) pk[cc] = (__bf16)acc2[pp][cc];
            *(bf16x4*)(gxb + n * 32 + tc * 4) = pk;
        }
    }
}

// ---------------------------------------------------------------------------
// Kernel B: 16 sparse points / 256-thread block.
// phase1 reordered for register pressure: weightnet chain (v dies early),
// then pe, then gathers. Gathers read bf16 rows (1 cache line each).
// phase4: direct global stores (LDS out-staging reverted: tripled bank
// conflicts, WRITE_SIZE unchanged -> it was never a coalescing problem).
// ---------------------------------------------------------------------------
struct SmemU {
    union {
        struct { __bf16 nfb[16][16][40]; __bf16 w3b[16][16][24]; } a; // 32768 B
        __bf16 aggB[16][520];                                         // 16640 B
    };
};

__global__ __launch_bounds__(256, 4) void pcf_kernel(
    const float* __restrict__ vi, const int* __restrict__ nei,
    const float* __restrict__ fx, const __bf16* __restrict__ gxb,
    const __bf16* __restrict__ dfb,
    const float* __restrict__ wpe, const float* __restrict__ bpe,
    const float* __restrict__ wg1, const float* __restrict__ bg1,
    const float* __restrict__ wg2, const float* __restrict__ bg2,
    const float* __restrict__ wn1, const float* __restrict__ bn1,
    const float* __restrict__ wn2, const float* __restrict__ bn2,
    const float* __restrict__ wn3, const float* __restrict__ bn3,
    const __bf16* __restrict__ wlinT, const float* __restrict__ blin,
    const __bf16* __restrict__ wu2T, const float* __restrict__ bu2,
    const __bf16* __restrict__ wscT, const float* __restrict__ bsc,
    float* __restrict__ out, int M)
{
    __shared__ SmemU U;
    __shared__ __bf16 sO[16][72];     // out64, padded rows (144B)
    __shared__ __bf16 sS[16][72];     // shortcut maxpool
    __shared__ int sInd[16][16];

    int t = threadIdx.x;
    int p = t >> 4, q = t & 15;
    long mbase = (long)blockIdx.x * 16;
    long m = mbase + p;
    bool okm = m < (long)M;
    int ind = okm ? nei[m * 16 + q] : 0;
    sInd[p][q] = ind;                 // consumed within the same wave only

    // ---------------- phase 1 ----------------
    float v[12];
    {
        const float4* v4 = (const float4*)(vi + (okm ? (m * 16 + q) * 12 : 0));
        float4 a = v4[0], b = v4[1], cc = v4[2];
        v[0] = a.x; v[1] = a.y; v[2] = a.z; v[3] = a.w;
        v[4] = b.x; v[5] = b.y; v[6] = b.z; v[7] = b.w;
        v[8] = cc.x; v[9] = cc.y; v[10] = cc.z; v[11] = cc.w;
    }
    // weightnet chain first: v dies before pe/gd go live (register pressure)
    {
        float wa[8], wb[8];
#pragma unroll
        for (int j = 0; j < 8; j++) {
            float a = bn1[j];
#pragma unroll
            for (int i = 0; i < 12; i++) a += v[i] * wn1[i * 8 + j];
            wa[j] = fmaxf(a, 0.f);
        }
#pragma unroll
        for (int j = 0; j < 8; j++) {
            float a = bn2[j];
#pragma unroll
            for (int i = 0; i < 8; i++) a += wa[i] * wn2[i * 8 + j];
            wb[j] = fmaxf(a, 0.f);
        }
        float w3v[16];
#pragma unroll
        for (int j = 0; j < 16; j++) {
            float a = bn3[j];
#pragma unroll
            for (int i = 0; i < 8; i++) a += wb[i] * wn3[i * 16 + j];
            w3v[j] = fmaxf(a, 0.f);
        }
        bf16x8 wlo, whi;
#pragma unroll
        for (int jj = 0; jj < 8; jj++) { wlo[jj] = (__bf16)w3v[jj]; whi[jj] = (__bf16)w3v[8 + jj]; }
        *(bf16x8*)(&U.a.w3b[p][q][0]) = wlo;
        *(bf16x8*)(&U.a.w3b[p][q][8]) = whi;
    }
    float pe[32];
#pragma unroll
    for (int c = 0; c < 32; c++) {
        float a = bpe[c];
#pragma unroll
        for (int i = 0; i < 12; i++) a += v[i] * wpe[i * 32 + c];
        pe[c] = fmaxf(a, 0.f);
    }
    // gathered guidance row (bf16, one cache line)
    float gd[32];
    {
        const bf16x8* g8 = (const bf16x8*)(gxb + (long)ind * 32);
#pragma unroll
        for (int c8 = 0; c8 < 4; c8++) {
            bf16x8 g = g8[c8];
#pragma unroll
            for (int e = 0; e < 8; e++) gd[c8 * 8 + e] = (float)g[e];
        }
    }
    float s1[8];
#pragma unroll
    for (int j = 0; j < 8; j++) s1[j] = bg1[j];
#pragma unroll
    for (int i = 0; i < 64; i++) {
        float gi = (i < 32) ? gd[i] : pe[i - 32];
        float sub = gi - rowmax16(gi);
#pragma unroll
        for (int j = 0; j < 8; j++) s1[j] += sub * wg1[i * 8 + j];
    }
#pragma unroll
    for (int j = 0; j < 8; j++) s1[j] = fmaxf(s1[j], 0.f);
    float s2[8];
#pragma unroll
    for (int j = 0; j < 8; j++) {
        float a = bg2[j];
#pragma unroll
        for (int i = 0; i < 8; i++) a += s1[i] * wg2[i * 8 + j];
        s2[j] = 1.f / (1.f + __expf(-a));
    }
    {
        const float4* f4 = (const float4*)(fx + (long)ind * 32);
        float nfv[32];
#pragma unroll
        for (int c8 = 0; c8 < 8; c8++) {
            float4 f = f4[c8];
            float s = s2[c8];
            nfv[c8 * 4 + 0] = f.x * s; nfv[c8 * 4 + 1] = f.y * s;
            nfv[c8 * 4 + 2] = f.z * s; nfv[c8 * 4 + 3] = f.w * s;
        }
#pragma unroll
        for (int g = 0; g < 4; g++) {
            bf16x8 pk;
#pragma unroll
            for (int e = 0; e < 8; e++) pk[e] = (__bf16)nfv[g * 8 + e];
            *(bf16x8*)(&U.a.nfb[p][q][g * 8]) = pk;
        }
    }
    // shortcut maxpool over bf16 df rows (exact vs f32-max-then-round)
    {
        float4 mx = make_float4(-1e30f, -1e30f, -1e30f, -1e30f);
#pragma unroll
        for (int kk = 0; kk < 16; kk++) {
            int ik = sInd[p][kk];
            bf16x4 d = *(const bf16x4*)(dfb + (long)ik * 64 + q * 4);
            mx.x = fmaxf(mx.x, (float)d[0]); mx.y = fmaxf(mx.y, (float)d[1]);
            mx.z = fmaxf(mx.z, (float)d[2]); mx.w = fmaxf(mx.w, (float)d[3]);
        }
        bf16x4 pk;
        pk[0] = (__bf16)mx.x; pk[1] = (__bf16)mx.y; pk[2] = (__bf16)mx.z; pk[3] = (__bf16)mx.w;
        *(bf16x4*)(&sS[p][q * 4]) = pk;
    }
    __syncthreads();

    // ---------------- phase 2: agg[p][k], k = c*16 + j ----------------
    {
        int chalf = q >> 1, j0 = (q & 1) * 8;
        float acc[4][8];
#pragma unroll
        for (int c4 = 0; c4 < 4; c4++)
#pragma unroll
            for (int j = 0; j < 8; j++) acc[c4][j] = 0.f;
#pragma unroll
        for (int kk = 0; kk < 16; kk++) {
            bf16x8 w8 = *(const bf16x8*)(&U.a.w3b[p][kk][j0]);
            float wf[8];
#pragma unroll
            for (int e = 0; e < 8; e++) wf[e] = (float)w8[e];
#pragma unroll
            for (int c4 = 0; c4 < 4; c4++) {
                float nfc = (float)U.a.nfb[p][kk][c4 * 8 + chalf];
#pragma unroll
                for (int j = 0; j < 8; j++) acc[c4][j] += nfc * wf[j];
            }
        }
        __syncthreads();          // all union-a reads complete before overwrite
#pragma unroll
        for (int c4 = 0; c4 < 4; c4++) {
            bf16x8 pk;
#pragma unroll
            for (int j = 0; j < 8; j++) pk[j] = (__bf16)acc[c4][j];
            *(bf16x8*)(&U.aggB[p][c4 * 128 + q * 8]) = pk;
        }
    }
    __syncthreads();

    // ---------------- phase 3: out64 = relu(agg @ wlin + blin), MFMA --------
    {
        int wv = t >> 6, ln = t & 63;
        int n = ln & 15, quad = ln >> 4;
        const __bf16* Bp = wlinT + ((wv * 16 + n) * 512 + quad * 8);
        f32x4 acc = {0.f, 0.f, 0.f, 0.f};
#pragma unroll
        for (int kk = 0; kk < 16; kk++) {
            bf16x8 a = *(const bf16x8*)(&U.aggB[n][kk * 32 + quad * 8]);
            bf16x8 b = *(const bf16x8*)(Bp + kk * 32);
            acc = __builtin_amdgcn_mfma_f32_16x16x32_bf16(a, b, acc, 0, 0, 0);
        }
        int col = wv * 16 + n;
        float bl = blin[col];
#pragma unroll
        for (int r = 0; r < 4; r++) {
            int row = quad * 4 + r;
            sO[row][col] = (__bf16)fmaxf(acc[r] + bl, 0.f);
        }
    }
    __syncthreads();

    // ---------------- phase 4: out = leaky(out64@wu2 + sf@wsc + b), MFMA ----
    {
        int wv = t >> 6, ln = t & 63;
        int n = ln & 15, quad = ln >> 4;
        bf16x8 aO0 = *(const bf16x8*)(&sO[n][quad * 8]);
        bf16x8 aO1 = *(const bf16x8*)(&sO[n][32 + quad * 8]);
        bf16x8 aS0 = *(const bf16x8*)(&sS[n][quad * 8]);
        bf16x8 aS1 = *(const bf16x8*)(&sS[n][32 + quad * 8]);
#pragma unroll
        for (int tt = 0; tt < 2; tt++) {
            int T = wv * 2 + tt;
            int col = T * 16 + n;
            const __bf16* B1 = wu2T + (col * 64 + quad * 8);
            const __bf16* B2 = wscT + (col * 64 + quad * 8);
            f32x4 acc = {0.f, 0.f, 0.f, 0.f};
            acc = __builtin_amdgcn_mfma_f32_16x16x32_bf16(aO0, *(const bf16x8*)(B1), acc, 0, 0, 0);
            acc = __builtin_amdgcn_mfma_f32_16x16x32_bf16(aO1, *(const bf16x8*)(B1 + 32), acc, 0, 0, 0);
            acc = __builtin_amdgcn_mfma_f32_16x16x32_bf16(aS0, *(const bf16x8*)(B2), acc, 0, 0, 0);
            acc = __builtin_amdgcn_mfma_f32_16x16x32_bf16(aS1, *(const bf16x8*)(B2 + 32), acc, 0, 0, 0);
            float bb = bu2[col] + bsc[col];
#pragma unroll
            for (int r = 0; r < 4; r++) {
                long mm = mbase + quad * 4 + r;
                if (mm < (long)M) {
                    float x = acc[r] + bb;
                    out[mm * 128 + col] = x > 0.f ? x : 0.1f * x;
                }
            }
        }
    }
}

extern "C" void kernel_launch(void* const* d_in, const int* in_sizes, int n_in,
                              void* d_out, int out_size, void* d_ws, size_t ws_size,
                              hipStream_t stream)
{
    const float* dense_feats = (const float*)d_in[1];
    const float* vi    = (const float*)d_in[5];
    const int*   nei   = (const int*)d_in[6];
    const float* w_u1  = (const float*)d_in[7];
    const float* b_u1  = (const float*)d_in[8];
    const float* w_gu  = (const float*)d_in[9];
    const float* b_gu  = (const float*)d_in[10];
    const float* w_pe  = (const float*)d_in[11];
    const float* b_pe  = (const float*)d_in[12];
    const float* w_g1  = (const float*)d_in[13];
    const float* b_g1  = (const float*)d_in[14];
    const float* w_g2  = (const float*)d_in[15];
    const float* b_g2  = (const float*)d_in[16];
    const float* w_wn1 = (const float*)d_in[17];
    const float* b_wn1 = (const float*)d_in[18];
    const float* w_wn2 = (const float*)d_in[19];
    const float* b_wn2 = (const float*)d_in[20];
    const float* w_wn3 = (const float*)d_in[21];
    const float* b_wn3 = (const float*)d_in[22];
    const float* w_lin = (const float*)d_in[23];
    const float* b_lin = (const float*)d_in[24];
    const float* w_u2  = (const float*)d_in[25];
    const float* b_u2  = (const float*)d_in[26];
    const float* w_sc  = (const float*)d_in[27];
    const float* b_sc  = (const float*)d_in[28];

    int N = in_sizes[1] / 64;     // 200000
    int M = in_sizes[6] / 16;     // 100000

    float*  fx   = (float*)d_ws;                         // [N,32] f32
    __bf16* gxb  = (__bf16*)(fx + (size_t)N * 32);       // [N,32] bf16
    __bf16* dfb  = gxb + (size_t)N * 32;                 // [N,64] bf16
    __bf16* wlinT = dfb + (size_t)N * 64;                // [64,512]
    __bf16* wu2T  = wlinT + 64 * 512;                    // [128,64]
    __bf16* wscT  = wu2T + 128 * 64;                     // [128,64]

    prep_kernel<<<(64 * 512 + 2 * 128 * 64 + 255) / 256, 256, 0, stream>>>(
        w_lin, w_u2, w_sc, wlinT, wu2T, wscT);

    feats_kernel<<<(N + 127) / 128, 256, 0, stream>>>(
        dense_feats, w_u1, b_u1, w_gu, b_gu, fx, gxb, dfb, N);

    pcf_kernel<<<(M + 15) / 16, 256, 0, stream>>>(
        vi, nei, fx, gxb, dfb,
        w_pe, b_pe, w_g1, b_g1, w_g2, b_g2,
        w_wn1, b_wn1, w_wn2, b_wn2, w_wn3, b_wn3,
        wlinT, b_lin, wu2T, b_u2, wscT, b_sc,
        (float*)d_out, M);
}

// Round 4
// 443.487 us; speedup vs baseline: 1.7975x; 1.7975x over previous
//
#include <hip/hip_runtime.h>
#include <math.h>

typedef __attribute__((ext_vector_type(8))) __bf16 bf16x8;
typedef __attribute__((ext_vector_type(4))) __bf16 bf16x4;
typedef __attribute__((ext_vector_type(4))) float f32x4;

// max over the 16-lane group via DPP row rotations (VALU, not LDS pipe)
__device__ __forceinline__ float rowmax16(float x) {
    int xi = __builtin_bit_cast(int, x);
    float y;
    y = __builtin_bit_cast(float, __builtin_amdgcn_update_dpp(0, xi, 0x128, 0xf, 0xf, true)); // ror:8
    x = fmaxf(x, y); xi = __builtin_bit_cast(int, x);
    y = __builtin_bit_cast(float, __builtin_amdgcn_update_dpp(0, xi, 0x124, 0xf, 0xf, true)); // ror:4
    x = fmaxf(x, y); xi = __builtin_bit_cast(int, x);
    y = __builtin_bit_cast(float, __builtin_amdgcn_update_dpp(0, xi, 0x122, 0xf, 0xf, true)); // ror:2
    x = fmaxf(x, y); xi = __builtin_bit_cast(int, x);
    y = __builtin_bit_cast(float, __builtin_amdgcn_update_dpp(0, xi, 0x121, 0xf, 0xf, true)); // ror:1
    x = fmaxf(x, y);
    return x;
}

// ---------------------------------------------------------------------------
// prep: transpose + bf16-cast epilogue weights, plus feats weights:
//  w1Th/w1Tl [32][64] hi/lo split of w_unary1^T, wgT [32][32] = w_gu^T.
// ---------------------------------------------------------------------------
__global__ void prep_kernel(const float* __restrict__ wlin,
                            const float* __restrict__ wu2,
                            const float* __restrict__ wsc,
                            const float* __restrict__ w1,
                            const float* __restrict__ wg,
                            __bf16* __restrict__ wlinT,
                            __bf16* __restrict__ wu2T,
                            __bf16* __restrict__ wscT,
                            __bf16* __restrict__ w1Th,
                            __bf16* __restrict__ w1Tl,
                            __bf16* __restrict__ wgT)
{
    const int B0 = 64 * 512;              // wlinT
    const int B1 = B0 + 128 * 64;         // wu2T
    const int B2 = B1 + 128 * 64;         // wscT
    const int B3 = B2 + 32 * 64;          // w1Th/l
    const int B4 = B3 + 32 * 32;          // wgT
    int i = blockIdx.x * 256 + threadIdx.x;
    if (i < B0) {
        int l = i >> 9, k = i & 511;
        wlinT[i] = (__bf16)wlin[k * 64 + l];
    } else if (i < B1) {
        int j = i - B0; int co = j >> 6, kk = j & 63;
        wu2T[j] = (__bf16)wu2[kk * 128 + co];
    } else if (i < B2) {
        int j = i - B1; int co = j >> 6, kk = j & 63;
        wscT[j] = (__bf16)wsc[kk * 128 + co];
    } else if (i < B3) {
        int j = i - B2; int c = j >> 6, k = j & 63;
        float v = w1[k * 32 + c];
        __bf16 h = (__bf16)v;
        w1Th[j] = h;
        w1Tl[j] = (__bf16)(v - (float)h);
    } else if (i < B4) {
        int j = i - B3; int c = j >> 5, k = j & 31;
        wgT[j] = (__bf16)wg[k * 32 + c];
    }
}

// ---------------------------------------------------------------------------
// Kernel A v4: MFMA. Every VALU formulation died on the LDS pipe (v1,
// ~3 ds_read per 2 FMA) or the register file (v2/v3, 256-VGPR spill ->
// 900MB scratch traffic). This is matmul-shaped compute: 16x16x32 bf16 MFMA
// needs 14 MFMA per 16 points, fragments fit in ~24 VGPRs.
// GEMM1 (fx path) uses hi/lo split-precision on both A and W (3 product
// terms) -> ~fp32 accuracy. GEMM2 (gx path) is plain bf16 (gx was already
// stored bf16 with no absmax change).
// Block = 4 waves x 16 points = 64 points. Grid 3125 (exact).
// ---------------------------------------------------------------------------
__global__ __launch_bounds__(256) void feats_kernel(
    const float* __restrict__ df,
    const __bf16* __restrict__ w1Th, const __bf16* __restrict__ w1Tl,
    const float* __restrict__ b1,
    const __bf16* __restrict__ wgT, const float* __restrict__ bg,
    float* __restrict__ fx, __bf16* __restrict__ gxb,
    __bf16* __restrict__ dfb, int N)
{
    __shared__ __bf16 sFx[4][16][40];   // per-wave fx tile (bf16), padded rows
    int t = threadIdx.x;
    int wv = t >> 6, ln = t & 63;
    int row = ln & 15, quad = ln >> 4;
    long n0 = (long)blockIdx.x * 64 + wv * 16;
    long n = n0 + row;                  // this lane's A-row (point)
    bool ok = n < (long)N;

    // ---- load df row fragment: k-octets quad (ks=0) and 32+quad*8 (ks=1)
    const float4* dp = (const float4*)(df + (ok ? n * 64 : 0));
    float4 f00 = dp[quad * 2 + 0], f01 = dp[quad * 2 + 1];
    float4 f10 = dp[8 + quad * 2 + 0], f11 = dp[8 + quad * 2 + 1];
    float s0[8] = {f00.x, f00.y, f00.z, f00.w, f01.x, f01.y, f01.z, f01.w};
    float s1[8] = {f10.x, f10.y, f10.z, f10.w, f11.x, f11.y, f11.z, f11.w};
    bf16x8 aH0, aL0, aH1, aL1;
#pragma unroll
    for (int e = 0; e < 8; e++) {
        __bf16 h = (__bf16)s0[e]; aH0[e] = h; aL0[e] = (__bf16)(s0[e] - (float)h);
        __bf16 g = (__bf16)s1[e]; aH1[e] = g; aL1[e] = (__bf16)(s1[e] - (float)g);
    }
    // dfb = bf16(df): hi parts are exactly that
    if (ok) {
        *(bf16x8*)(dfb + n * 64 + quad * 8) = aH0;
        *(bf16x8*)(dfb + n * 64 + 32 + quad * 8) = aH1;
    }

    // ---- GEMM1: fx[16][32] = leaky(df @ w1 + b1), split-precision MFMA
    const __bf16* bh = w1Th + (row * 64 + quad * 8);   // col = row (lane&15)
    const __bf16* bl = w1Tl + (row * 64 + quad * 8);
    f32x4 acc0 = {0.f, 0.f, 0.f, 0.f}, acc1 = {0.f, 0.f, 0.f, 0.f};
    {
        bf16x8 bH00 = *(const bf16x8*)(bh);             // ct=0 ks=0
        bf16x8 bH01 = *(const bf16x8*)(bh + 32);        // ct=0 ks=1
        bf16x8 bH10 = *(const bf16x8*)(bh + 16 * 64);   // ct=1 ks=0
        bf16x8 bH11 = *(const bf16x8*)(bh + 16 * 64 + 32);
        bf16x8 bL00 = *(const bf16x8*)(bl);
        bf16x8 bL01 = *(const bf16x8*)(bl + 32);
        bf16x8 bL10 = *(const bf16x8*)(bl + 16 * 64);
        bf16x8 bL11 = *(const bf16x8*)(bl + 16 * 64 + 32);
        acc0 = __builtin_amdgcn_mfma_f32_16x16x32_bf16(aH0, bH00, acc0, 0, 0, 0);
        acc0 = __builtin_amdgcn_mfma_f32_16x16x32_bf16(aH1, bH01, acc0, 0, 0, 0);
        acc0 = __builtin_amdgcn_mfma_f32_16x16x32_bf16(aL0, bH00, acc0, 0, 0, 0);
        acc0 = __builtin_amdgcn_mfma_f32_16x16x32_bf16(aL1, bH01, acc0, 0, 0, 0);
        acc0 = __builtin_amdgcn_mfma_f32_16x16x32_bf16(aH0, bL00, acc0, 0, 0, 0);
        acc0 = __builtin_amdgcn_mfma_f32_16x16x32_bf16(aH1, bL01, acc0, 0, 0, 0);
        acc1 = __builtin_amdgcn_mfma_f32_16x16x32_bf16(aH0, bH10, acc1, 0, 0, 0);
        acc1 = __builtin_amdgcn_mfma_f32_16x16x32_bf16(aH1, bH11, acc1, 0, 0, 0);
        acc1 = __builtin_amdgcn_mfma_f32_16x16x32_bf16(aL0, bH10, acc1, 0, 0, 0);
        acc1 = __builtin_amdgcn_mfma_f32_16x16x32_bf16(aL1, bH11, acc1, 0, 0, 0);
        acc1 = __builtin_amdgcn_mfma_f32_16x16x32_bf16(aH0, bL10, acc1, 0, 0, 0);
        acc1 = __builtin_amdgcn_mfma_f32_16x16x32_bf16(aH1, bL11, acc1, 0, 0, 0);
    }
    // epilogue: D[point = quad*4+r][col = ct*16+row]
    {
        float bb0 = b1[row], bb1 = b1[16 + row];
#pragma unroll
        for (int r = 0; r < 4; r++) {
            long np = n0 + quad * 4 + r;
            float x0 = acc0[r] + bb0; x0 = x0 > 0.f ? x0 : 0.1f * x0;
            float x1 = acc1[r] + bb1; x1 = x1 > 0.f ? x1 : 0.1f * x1;
            if (np < (long)N) {
                fx[np * 32 + row] = x0;
                fx[np * 32 + 16 + row] = x1;
            }
            sFx[wv][quad * 4 + r][row] = (__bf16)x0;
            sFx[wv][quad * 4 + r][16 + row] = (__bf16)x1;
        }
    }
    // same-wave LDS dependency: compiler inserts lgkmcnt; no barrier needed
    // (each wave uses only its own sFx[wv] slice)
    __builtin_amdgcn_s_waitcnt(0);   // lgkmcnt(0)+vmcnt(0): cheap, safe

    // ---- GEMM2: gx[16][32] = fx @ wg + bg, plain bf16
    {
        bf16x8 a2 = *(const bf16x8*)(&sFx[wv][row][quad * 8]);
        bf16x8 b20 = *(const bf16x8*)(wgT + row * 32 + quad * 8);
        bf16x8 b21 = *(const bf16x8*)(wgT + (16 + row) * 32 + quad * 8);
        f32x4 g0 = {0.f, 0.f, 0.f, 0.f}, g1 = {0.f, 0.f, 0.f, 0.f};
        g0 = __builtin_amdgcn_mfma_f32_16x16x32_bf16(a2, b20, g0, 0, 0, 0);
        g1 = __builtin_amdgcn_mfma_f32_16x16x32_bf16(a2, b21, g1, 0, 0, 0);
        float bb0 = bg[row], bb1 = bg[16 + row];
#pragma unroll
        for (int r = 0; r < 4; r++) {
            long np = n0 + quad * 4 + r;
            if (np < (long)N) {
                gxb[np * 32 + row] = (__bf16)(g0[r] + bb0);
                gxb[np * 32 + 16 + row] = (__bf16)(g1[r] + bb1);
            }
        }
    }
}

// ---------------------------------------------------------------------------
// Kernel B: 16 sparse points / 256-thread block. (unchanged from round 2)
// ---------------------------------------------------------------------------
struct SmemU {
    union {
        struct { __bf16 nfb[16][16][40]; __bf16 w3b[16][16][24]; } a; // 32768 B
        __bf16 aggB[16][520];                                         // 16640 B
    };
};

__global__ __launch_bounds__(256, 4) void pcf_kernel(
    const float* __restrict__ vi, const int* __restrict__ nei,
    const float* __restrict__ fx, const __bf16* __restrict__ gxb,
    const __bf16* __restrict__ dfb,
    const float* __restrict__ wpe, const float* __restrict__ bpe,
    const float* __restrict__ wg1, const float* __restrict__ bg1,
    const float* __restrict__ wg2, const float* __restrict__ bg2,
    const float* __restrict__ wn1, const float* __restrict__ bn1,
    const float* __restrict__ wn2, const float* __restrict__ bn2,
    const float* __restrict__ wn3, const float* __restrict__ bn3,
    const __bf16* __restrict__ wlinT, const float* __restrict__ blin,
    const __bf16* __restrict__ wu2T, const float* __restrict__ bu2,
    const __bf16* __restrict__ wscT, const float* __restrict__ bsc,
    float* __restrict__ out, int M)
{
    __shared__ SmemU U;
    __shared__ __bf16 sO[16][72];     // out64, padded rows (144B)
    __shared__ __bf16 sS[16][72];     // shortcut maxpool
    __shared__ int sInd[16][16];

    int t = threadIdx.x;
    int p = t >> 4, q = t & 15;
    long mbase = (long)blockIdx.x * 16;
    long m = mbase + p;
    bool okm = m < (long)M;
    int ind = okm ? nei[m * 16 + q] : 0;
    sInd[p][q] = ind;                 // consumed within the same wave only

    // ---------------- phase 1 ----------------
    float v[12];
    {
        const float4* v4 = (const float4*)(vi + (okm ? (m * 16 + q) * 12 : 0));
        float4 a = v4[0], b = v4[1], cc = v4[2];
        v[0] = a.x; v[1] = a.y; v[2] = a.z; v[3] = a.w;
        v[4] = b.x; v[5] = b.y; v[6] = b.z; v[7] = b.w;
        v[8] = cc.x; v[9] = cc.y; v[10] = cc.z; v[11] = cc.w;
    }
    // weightnet chain first: v dies before pe/gd go live (register pressure)
    {
        float wa[8], wb[8];
#pragma unroll
        for (int j = 0; j < 8; j++) {
            float a = bn1[j];
#pragma unroll
            for (int i = 0; i < 12; i++) a += v[i] * wn1[i * 8 + j];
            wa[j] = fmaxf(a, 0.f);
        }
#pragma unroll
        for (int j = 0; j < 8; j++) {
            float a = bn2[j];
#pragma unroll
            for (int i = 0; i < 8; i++) a += wa[i] * wn2[i * 8 + j];
            wb[j] = fmaxf(a, 0.f);
        }
        float w3v[16];
#pragma unroll
        for (int j = 0; j < 16; j++) {
            float a = bn3[j];
#pragma unroll
            for (int i = 0; i < 8; i++) a += wb[i] * wn3[i * 16 + j];
            w3v[j] = fmaxf(a, 0.f);
        }
        bf16x8 wlo, whi;
#pragma unroll
        for (int jj = 0; jj < 8; jj++) { wlo[jj] = (__bf16)w3v[jj]; whi[jj] = (__bf16)w3v[8 + jj]; }
        *(bf16x8*)(&U.a.w3b[p][q][0]) = wlo;
        *(bf16x8*)(&U.a.w3b[p][q][8]) = whi;
    }
    float pe[32];
#pragma unroll
    for (int c = 0; c < 32; c++) {
        float a = bpe[c];
#pragma unroll
        for (int i = 0; i < 12; i++) a += v[i] * wpe[i * 32 + c];
        pe[c] = fmaxf(a, 0.f);
    }
    // gathered guidance row (bf16, one cache line)
    float gd[32];
    {
        const bf16x8* g8 = (const bf16x8*)(gxb + (long)ind * 32);
#pragma unroll
        for (int c8 = 0; c8 < 4; c8++) {
            bf16x8 g = g8[c8];
#pragma unroll
            for (int e = 0; e < 8; e++) gd[c8 * 8 + e] = (float)g[e];
        }
    }
    float s1[8];
#pragma unroll
    for (int j = 0; j < 8; j++) s1[j] = bg1[j];
#pragma unroll
    for (int i = 0; i < 64; i++) {
        float gi = (i < 32) ? gd[i] : pe[i - 32];
        float sub = gi - rowmax16(gi);
#pragma unroll
        for (int j = 0; j < 8; j++) s1[j] += sub * wg1[i * 8 + j];
    }
#pragma unroll
    for (int j = 0; j < 8; j++) s1[j] = fmaxf(s1[j], 0.f);
    float s2[8];
#pragma unroll
    for (int j = 0; j < 8; j++) {
        float a = bg2[j];
#pragma unroll
        for (int i = 0; i < 8; i++) a += s1[i] * wg2[i * 8 + j];
        s2[j] = 1.f / (1.f + __expf(-a));
    }
    {
        const float4* f4 = (const float4*)(fx + (long)ind * 32);
        float nfv[32];
#pragma unroll
        for (int c8 = 0; c8 < 8; c8++) {
            float4 f = f4[c8];
            float s = s2[c8];
            nfv[c8 * 4 + 0] = f.x * s; nfv[c8 * 4 + 1] = f.y * s;
            nfv[c8 * 4 + 2] = f.z * s; nfv[c8 * 4 + 3] = f.w * s;
        }
#pragma unroll
        for (int g = 0; g < 4; g++) {
            bf16x8 pk;
#pragma unroll
            for (int e = 0; e < 8; e++) pk[e] = (__bf16)nfv[g * 8 + e];
            *(bf16x8*)(&U.a.nfb[p][q][g * 8]) = pk;
        }
    }
    // shortcut maxpool over bf16 df rows (exact vs f32-max-then-round)
    {
        float4 mx = make_float4(-1e30f, -1e30f, -1e30f, -1e30f);
#pragma unroll
        for (int kk = 0; kk < 16; kk++) {
            int ik = sInd[p][kk];
            bf16x4 d = *(const bf16x4*)(dfb + (long)ik * 64 + q * 4);
            mx.x = fmaxf(mx.x, (float)d[0]); mx.y = fmaxf(mx.y, (float)d[1]);
            mx.z = fmaxf(mx.z, (float)d[2]); mx.w = fmaxf(mx.w, (float)d[3]);
        }
        bf16x4 pk;
        pk[0] = (__bf16)mx.x; pk[1] = (__bf16)mx.y; pk[2] = (__bf16)mx.z; pk[3] = (__bf16)mx.w;
        *(bf16x4*)(&sS[p][q * 4]) = pk;
    }
    __syncthreads();

    // ---------------- phase 2: agg[p][k], k = c*16 + j ----------------
    {
        int chalf = q >> 1, j0 = (q & 1) * 8;
        float acc[4][8];
#pragma unroll
        for (int c4 = 0; c4 < 4; c4++)
#pragma unroll
            for (int j = 0; j < 8; j++) acc[c4][j] = 0.f;
#pragma unroll
        for (int kk = 0; kk < 16; kk++) {
            bf16x8 w8 = *(const bf16x8*)(&U.a.w3b[p][kk][j0]);
            float wf[8];
#pragma unroll
            for (int e = 0; e < 8; e++) wf[e] = (float)w8[e];
#pragma unroll
            for (int c4 = 0; c4 < 4; c4++) {
                float nfc = (float)U.a.nfb[p][kk][c4 * 8 + chalf];
#pragma unroll
                for (int j = 0; j < 8; j++) acc[c4][j] += nfc * wf[j];
            }
        }
        __syncthreads();          // all union-a reads complete before overwrite
#pragma unroll
        for (int c4 = 0; c4 < 4; c4++) {
            bf16x8 pk;
#pragma unroll
            for (int j = 0; j < 8; j++) pk[j] = (__bf16)acc[c4][j];
            *(bf16x8*)(&U.aggB[p][c4 * 128 + q * 8]) = pk;
        }
    }
    __syncthreads();

    // ---------------- phase 3: out64 = relu(agg @ wlin + blin), MFMA --------
    {
        int wv = t >> 6, ln = t & 63;
        int n = ln & 15, quad = ln >> 4;
        const __bf16* Bp = wlinT + ((wv * 16 + n) * 512 + quad * 8);
        f32x4 acc = {0.f, 0.f, 0.f, 0.f};
#pragma unroll
        for (int kk = 0; kk < 16; kk++) {
            bf16x8 a = *(const bf16x8*)(&U.aggB[n][kk * 32 + quad * 8]);
            bf16x8 b = *(const bf16x8*)(Bp + kk * 32);
            acc = __builtin_amdgcn_mfma_f32_16x16x32_bf16(a, b, acc, 0, 0, 0);
        }
        int col = wv * 16 + n;
        float bl = blin[col];
#pragma unroll
        for (int r = 0; r < 4; r++) {
            int row = quad * 4 + r;
            sO[row][col] = (__bf16)fmaxf(acc[r] + bl, 0.f);
        }
    }
    __syncthreads();

    // ---------------- phase 4: out = leaky(out64@wu2 + sf@wsc + b), MFMA ----
    {
        int wv = t >> 6, ln = t & 63;
        int n = ln & 15, quad = ln >> 4;
        bf16x8 aO0 = *(const bf16x8*)(&sO[n][quad * 8]);
        bf16x8 aO1 = *(const bf16x8*)(&sO[n][32 + quad * 8]);
        bf16x8 aS0 = *(const bf16x8*)(&sS[n][quad * 8]);
        bf16x8 aS1 = *(const bf16x8*)(&sS[n][32 + quad * 8]);
#pragma unroll
        for (int tt = 0; tt < 2; tt++) {
            int T = wv * 2 + tt;
            int col = T * 16 + n;
            const __bf16* B1 = wu2T + (col * 64 + quad * 8);
            const __bf16* B2 = wscT + (col * 64 + quad * 8);
            f32x4 acc = {0.f, 0.f, 0.f, 0.f};
            acc = __builtin_amdgcn_mfma_f32_16x16x32_bf16(aO0, *(const bf16x8*)(B1), acc, 0, 0, 0);
            acc = __builtin_amdgcn_mfma_f32_16x16x32_bf16(aO1, *(const bf16x8*)(B1 + 32), acc, 0, 0, 0);
            acc = __builtin_amdgcn_mfma_f32_16x16x32_bf16(aS0, *(const bf16x8*)(B2), acc, 0, 0, 0);
            acc = __builtin_amdgcn_mfma_f32_16x16x32_bf16(aS1, *(const bf16x8*)(B2 + 32), acc, 0, 0, 0);
            float bb = bu2[col] + bsc[col];
#pragma unroll
            for (int r = 0; r < 4; r++) {
                long mm = mbase + quad * 4 + r;
                if (mm < (long)M) {
                    float x = acc[r] + bb;
                    out[mm * 128 + col] = x > 0.f ? x : 0.1f * x;
                }
            }
        }
    }
}

extern "C" void kernel_launch(void* const* d_in, const int* in_sizes, int n_in,
                              void* d_out, int out_size, void* d_ws, size_t ws_size,
                              hipStream_t stream)
{
    const float* dense_feats = (const float*)d_in[1];
    const float* vi    = (const float*)d_in[5];
    const int*   nei   = (const int*)d_in[6];
    const float* w_u1  = (const float*)d_in[7];
    const float* b_u1  = (const float*)d_in[8];
    const float* w_gu  = (const float*)d_in[9];
    const float* b_gu  = (const float*)d_in[10];
    const float* w_pe  = (const float*)d_in[11];
    const float* b_pe  = (const float*)d_in[12];
    const float* w_g1  = (const float*)d_in[13];
    const float* b_g1  = (const float*)d_in[14];
    const float* w_g2  = (const float*)d_in[15];
    const float* b_g2  = (const float*)d_in[16];
    const float* w_wn1 = (const float*)d_in[17];
    const float* b_wn1 = (const float*)d_in[18];
    const float* w_wn2 = (const float*)d_in[19];
    const float* b_wn2 = (const float*)d_in[20];
    const float* w_wn3 = (const float*)d_in[21];
    const float* b_wn3 = (const float*)d_in[22];
    const float* w_lin = (const float*)d_in[23];
    const float* b_lin = (const float*)d_in[24];
    const float* w_u2  = (const float*)d_in[25];
    const float* b_u2  = (const float*)d_in[26];
    const float* w_sc  = (const float*)d_in[27];
    const float* b_sc  = (const float*)d_in[28];

    int N = in_sizes[1] / 64;     // 200000
    int M = in_sizes[6] / 16;     // 100000

    float*  fx   = (float*)d_ws;                         // [N,32] f32
    __bf16* gxb  = (__bf16*)(fx + (size_t)N * 32);       // [N,32] bf16
    __bf16* dfb  = gxb + (size_t)N * 32;                 // [N,64] bf16
    __bf16* wlinT = dfb + (size_t)N * 64;                // [64,512]
    __bf16* wu2T  = wlinT + 64 * 512;                    // [128,64]
    __bf16* wscT  = wu2T + 128 * 64;                     // [128,64]
    __bf16* w1Th  = wscT + 128 * 64;                     // [32,64]
    __bf16* w1Tl  = w1Th + 32 * 64;                      // [32,64]
    __bf16* wgT   = w1Tl + 32 * 64;                      // [32,32]

    const int prep_items = 64 * 512 + 2 * 128 * 64 + 2 * 32 * 64 + 32 * 32;
    prep_kernel<<<(prep_items + 255) / 256, 256, 0, stream>>>(
        w_lin, w_u2, w_sc, w_u1, w_gu, wlinT, wu2T, wscT, w1Th, w1Tl, wgT);

    feats_kernel<<<(N + 63) / 64, 256, 0, stream>>>(
        dense_feats, w1Th, w1Tl, b_u1, wgT, b_gu, fx, gxb, dfb, N);

    pcf_kernel<<<(M + 15) / 16, 256, 0, stream>>>(
        vi, nei, fx, gxb, dfb,
        w_pe, b_pe, w_g1, b_g1, w_g2, b_g2,
        w_wn1, b_wn1, w_wn2, b_wn2, w_wn3, b_wn3,
        wlinT, b_lin, wu2T, b_u2, wscT, b_sc,
        (float*)d_out, M);
}

// Round 6
// 378.782 us; speedup vs baseline: 2.1045x; 1.1708x over previous
//
#include <hip/hip_runtime.h>
#include <math.h>

typedef __attribute__((ext_vector_type(8))) __bf16 bf16x8;
typedef __attribute__((ext_vector_type(4))) __bf16 bf16x4;
typedef __attribute__((ext_vector_type(4))) float f32x4;

// max over the 16-lane group via DPP row rotations (VALU, not LDS pipe)
__device__ __forceinline__ float rowmax16(float x) {
    int xi = __builtin_bit_cast(int, x);
    float y;
    y = __builtin_bit_cast(float, __builtin_amdgcn_update_dpp(0, xi, 0x128, 0xf, 0xf, true)); // ror:8
    x = fmaxf(x, y); xi = __builtin_bit_cast(int, x);
    y = __builtin_bit_cast(float, __builtin_amdgcn_update_dpp(0, xi, 0x124, 0xf, 0xf, true)); // ror:4
    x = fmaxf(x, y); xi = __builtin_bit_cast(int, x);
    y = __builtin_bit_cast(float, __builtin_amdgcn_update_dpp(0, xi, 0x122, 0xf, 0xf, true)); // ror:2
    x = fmaxf(x, y); xi = __builtin_bit_cast(int, x);
    y = __builtin_bit_cast(float, __builtin_amdgcn_update_dpp(0, xi, 0x121, 0xf, 0xf, true)); // ror:1
    x = fmaxf(x, y);
    return x;
}

// ---------------------------------------------------------------------------
// prep: transpose + bf16-cast epilogue weights, plus feats weights:
//  w1Th/w1Tl [32][64] hi/lo split of w_unary1^T, wgT [32][32] = w_gu^T.
// ---------------------------------------------------------------------------
__global__ void prep_kernel(const float* __restrict__ wlin,
                            const float* __restrict__ wu2,
                            const float* __restrict__ wsc,
                            const float* __restrict__ w1,
                            const float* __restrict__ wg,
                            __bf16* __restrict__ wlinT,
                            __bf16* __restrict__ wu2T,
                            __bf16* __restrict__ wscT,
                            __bf16* __restrict__ w1Th,
                            __bf16* __restrict__ w1Tl,
                            __bf16* __restrict__ wgT)
{
    const int B0 = 64 * 512;              // wlinT
    const int B1 = B0 + 128 * 64;         // wu2T
    const int B2 = B1 + 128 * 64;         // wscT
    const int B3 = B2 + 32 * 64;          // w1Th/l
    const int B4 = B3 + 32 * 32;          // wgT
    int i = blockIdx.x * 256 + threadIdx.x;
    if (i < B0) {
        int l = i >> 9, k = i & 511;
        wlinT[i] = (__bf16)wlin[k * 64 + l];
    } else if (i < B1) {
        int j = i - B0; int co = j >> 6, kk = j & 63;
        wu2T[j] = (__bf16)wu2[kk * 128 + co];
    } else if (i < B2) {
        int j = i - B1; int co = j >> 6, kk = j & 63;
        wscT[j] = (__bf16)wsc[kk * 128 + co];
    } else if (i < B3) {
        int j = i - B2; int c = j >> 6, k = j & 63;
        float v = w1[k * 32 + c];
        __bf16 h = (__bf16)v;
        w1Th[j] = h;
        w1Tl[j] = (__bf16)(v - (float)h);
    } else if (i < B4) {
        int j = i - B3; int c = j >> 5, k = j & 31;
        wgT[j] = (__bf16)wg[k * 32 + c];
    }
}

// ---------------------------------------------------------------------------
// Kernel A v5: MFMA feats (as v4) + bf16 fx output + LDS-staged coalesced
// stores for fxb/gxb (v4 scattered 2-4B scalar stores).
// ---------------------------------------------------------------------------
__global__ __launch_bounds__(256) void feats_kernel(
    const float* __restrict__ df,
    const __bf16* __restrict__ w1Th, const __bf16* __restrict__ w1Tl,
    const float* __restrict__ b1,
    const __bf16* __restrict__ wgT, const float* __restrict__ bg,
    __bf16* __restrict__ fxb, __bf16* __restrict__ gxb,
    __bf16* __restrict__ dfb, int N)
{
    __shared__ __bf16 sFx[4][16][40];   // per-wave tile, padded rows
    int t = threadIdx.x;
    int wv = t >> 6, ln = t & 63;
    int row = ln & 15, quad = ln >> 4;
    long n0 = (long)blockIdx.x * 64 + wv * 16;
    long n = n0 + row;                  // this lane's A-row (point)
    bool ok = n < (long)N;

    // ---- load df row fragment
    const float4* dp = (const float4*)(df + (ok ? n * 64 : 0));
    float4 f00 = dp[quad * 2 + 0], f01 = dp[quad * 2 + 1];
    float4 f10 = dp[8 + quad * 2 + 0], f11 = dp[8 + quad * 2 + 1];
    float s0[8] = {f00.x, f00.y, f00.z, f00.w, f01.x, f01.y, f01.z, f01.w};
    float s1[8] = {f10.x, f10.y, f10.z, f10.w, f11.x, f11.y, f11.z, f11.w};
    bf16x8 aH0, aL0, aH1, aL1;
#pragma unroll
    for (int e = 0; e < 8; e++) {
        __bf16 h = (__bf16)s0[e]; aH0[e] = h; aL0[e] = (__bf16)(s0[e] - (float)h);
        __bf16 g = (__bf16)s1[e]; aH1[e] = g; aL1[e] = (__bf16)(s1[e] - (float)g);
    }
    if (ok) {
        *(bf16x8*)(dfb + n * 64 + quad * 8) = aH0;
        *(bf16x8*)(dfb + n * 64 + 32 + quad * 8) = aH1;
    }

    // ---- GEMM1: fx = leaky(df @ w1 + b1), split-precision MFMA
    const __bf16* bh = w1Th + (row * 64 + quad * 8);
    const __bf16* bl = w1Tl + (row * 64 + quad * 8);
    f32x4 acc0 = {0.f, 0.f, 0.f, 0.f}, acc1 = {0.f, 0.f, 0.f, 0.f};
    {
        bf16x8 bH00 = *(const bf16x8*)(bh);
        bf16x8 bH01 = *(const bf16x8*)(bh + 32);
        bf16x8 bH10 = *(const bf16x8*)(bh + 16 * 64);
        bf16x8 bH11 = *(const bf16x8*)(bh + 16 * 64 + 32);
        bf16x8 bL00 = *(const bf16x8*)(bl);
        bf16x8 bL01 = *(const bf16x8*)(bl + 32);
        bf16x8 bL10 = *(const bf16x8*)(bl + 16 * 64);
        bf16x8 bL11 = *(const bf16x8*)(bl + 16 * 64 + 32);
        acc0 = __builtin_amdgcn_mfma_f32_16x16x32_bf16(aH0, bH00, acc0, 0, 0, 0);
        acc0 = __builtin_amdgcn_mfma_f32_16x16x32_bf16(aH1, bH01, acc0, 0, 0, 0);
        acc0 = __builtin_amdgcn_mfma_f32_16x16x32_bf16(aL0, bH00, acc0, 0, 0, 0);
        acc0 = __builtin_amdgcn_mfma_f32_16x16x32_bf16(aL1, bH01, acc0, 0, 0, 0);
        acc0 = __builtin_amdgcn_mfma_f32_16x16x32_bf16(aH0, bL00, acc0, 0, 0, 0);
        acc0 = __builtin_amdgcn_mfma_f32_16x16x32_bf16(aH1, bL01, acc0, 0, 0, 0);
        acc1 = __builtin_amdgcn_mfma_f32_16x16x32_bf16(aH0, bH10, acc1, 0, 0, 0);
        acc1 = __builtin_amdgcn_mfma_f32_16x16x32_bf16(aH1, bH11, acc1, 0, 0, 0);
        acc1 = __builtin_amdgcn_mfma_f32_16x16x32_bf16(aL0, bH10, acc1, 0, 0, 0);
        acc1 = __builtin_amdgcn_mfma_f32_16x16x32_bf16(aL1, bH11, acc1, 0, 0, 0);
        acc1 = __builtin_amdgcn_mfma_f32_16x16x32_bf16(aH0, bL10, acc1, 0, 0, 0);
        acc1 = __builtin_amdgcn_mfma_f32_16x16x32_bf16(aH1, bL11, acc1, 0, 0, 0);
    }
    // epilogue -> sFx (bf16) only; global fxb written coalesced below
    {
        float bb0 = b1[row], bb1 = b1[16 + row];
#pragma unroll
        for (int r = 0; r < 4; r++) {
            float x0 = acc0[r] + bb0; x0 = x0 > 0.f ? x0 : 0.1f * x0;
            float x1 = acc1[r] + bb1; x1 = x1 > 0.f ? x1 : 0.1f * x1;
            sFx[wv][quad * 4 + r][row] = (__bf16)x0;
            sFx[wv][quad * 4 + r][16 + row] = (__bf16)x1;
        }
    }
    __builtin_amdgcn_s_waitcnt(0);   // own-wave LDS handoff

    // ---- GEMM2: gx = fx @ wg + bg (bf16 MFMA)
    f32x4 g0 = {0.f, 0.f, 0.f, 0.f}, g1 = {0.f, 0.f, 0.f, 0.f};
    {
        bf16x8 a2 = *(const bf16x8*)(&sFx[wv][row][quad * 8]);
        bf16x8 b20 = *(const bf16x8*)(wgT + row * 32 + quad * 8);
        bf16x8 b21 = *(const bf16x8*)(wgT + (16 + row) * 32 + quad * 8);
        g0 = __builtin_amdgcn_mfma_f32_16x16x32_bf16(a2, b20, g0, 0, 0, 0);
        g1 = __builtin_amdgcn_mfma_f32_16x16x32_bf16(a2, b21, g1, 0, 0, 0);
    }
    // ---- coalesced fxb store (reads sFx before overwrite)
    {
        int r16 = ln >> 2, seg = ln & 3;
        bf16x8 vfx = *(const bf16x8*)(&sFx[wv][r16][seg * 8]);
        long nn = n0 + r16;
        if (nn < (long)N) *(bf16x8*)(fxb + nn * 32 + seg * 8) = vfx;
    }
    // ---- overwrite sFx with g-tile, then coalesced gxb store
    {
        float bb0 = bg[row], bb1 = bg[16 + row];
#pragma unroll
        for (int r = 0; r < 4; r++) {
            sFx[wv][quad * 4 + r][row] = (__bf16)(g0[r] + bb0);
            sFx[wv][quad * 4 + r][16 + row] = (__bf16)(g1[r] + bb1);
        }
    }
    __builtin_amdgcn_s_waitcnt(0);
    {
        int r16 = ln >> 2, seg = ln & 3;
        bf16x8 vg = *(const bf16x8*)(&sFx[wv][r16][seg * 8]);
        long nn = n0 + r16;
        if (nn < (long)N) *(bf16x8*)(gxb + nn * 32 + seg * 8) = vg;
    }
}

// ---------------------------------------------------------------------------
// Kernel B v5: phase-2 aggregation moved to MFMA.
// Phase 1 writes nf/w3 in MFMA fragment layouts (k-contiguous, XOR-swizzled):
//   nfF[p][ctile][c'][k] : B-frag = nf[k][ctile*16+c']  (b128 reads)
//   w3A[p][kq][j][e]     : A-frag = w3[kq*8+e][j]       (b128 reads)
// Phase 2: D[j][c] = sum_k w3[k][j]*nf[k][c] via 16x16x32 MFMA (K zero-padded
// to 32: quads 2-3 supply zero frags). D packed bf16x4 -> aggB (b64 writes).
// Barrier structure: frag reads (own-wave data) -> MFMA -> barrier ->
// aggB writes (overlap other waves' frag bytes) -> barrier -> phase 3.
// LDS 30208 B -> 5 blocks/CU (was 4).
// ---------------------------------------------------------------------------
struct SmemU {
    union {
        struct { __bf16 nfF[16 * 512]; __bf16 w3A[16 * 256]; } a; // 24576 B
        __bf16 aggB[16][520];                                     // 16640 B
    };
};

__global__ __launch_bounds__(256, 5) void pcf_kernel(
    const float* __restrict__ vi, const int* __restrict__ nei,
    const __bf16* __restrict__ fxb, const __bf16* __restrict__ gxb,
    const __bf16* __restrict__ dfb,
    const float* __restrict__ wpe, const float* __restrict__ bpe,
    const float* __restrict__ wg1, const float* __restrict__ bg1,
    const float* __restrict__ wg2, const float* __restrict__ bg2,
    const float* __restrict__ wn1, const float* __restrict__ bn1,
    const float* __restrict__ wn2, const float* __restrict__ bn2,
    const float* __restrict__ wn3, const float* __restrict__ bn3,
    const __bf16* __restrict__ wlinT, const float* __restrict__ blin,
    const __bf16* __restrict__ wu2T, const float* __restrict__ bu2,
    const __bf16* __restrict__ wscT, const float* __restrict__ bsc,
    float* __restrict__ out, int M)
{
    __shared__ SmemU U;
    __shared__ __bf16 sO[16][72];     // out64, padded rows
    __shared__ __bf16 sS[16][72];     // shortcut maxpool
    __shared__ int sInd[16][16];

    int t = threadIdx.x;
    int p = t >> 4, q = t & 15;
    long mbase = (long)blockIdx.x * 16;
    long m = mbase + p;
    bool okm = m < (long)M;
    int ind = okm ? nei[m * 16 + q] : 0;
    sInd[p][q] = ind;                 // consumed within the same wave only

    // ---------------- phase 1 ----------------
    float v[12];
    {
        const float4* v4 = (const float4*)(vi + (okm ? (m * 16 + q) * 12 : 0));
        float4 a = v4[0], b = v4[1], cc = v4[2];
        v[0] = a.x; v[1] = a.y; v[2] = a.z; v[3] = a.w;
        v[4] = b.x; v[5] = b.y; v[6] = b.z; v[7] = b.w;
        v[8] = cc.x; v[9] = cc.y; v[10] = cc.z; v[11] = cc.w;
    }
    // weightnet chain first (v dies early); write w3 in A-frag layout
    {
        float wa[8], wb[8];
#pragma unroll
        for (int j = 0; j < 8; j++) {
            float a = bn1[j];
#pragma unroll
            for (int i = 0; i < 12; i++) a += v[i] * wn1[i * 8 + j];
            wa[j] = fmaxf(a, 0.f);
        }
#pragma unroll
        for (int j = 0; j < 8; j++) {
            float a = bn2[j];
#pragma unroll
            for (int i = 0; i < 8; i++) a += wa[i] * wn2[i * 8 + j];
            wb[j] = fmaxf(a, 0.f);
        }
        int swz = (p & 3) << 4;
        int kb = (q >> 3) * 128 + (q & 7);
#pragma unroll
        for (int j = 0; j < 16; j++) {
            float a = bn3[j];
#pragma unroll
            for (int i = 0; i < 8; i++) a += wb[i] * wn3[i * 16 + j];
            U.a.w3A[p * 256 + ((kb + j * 8) ^ swz)] = (__bf16)fmaxf(a, 0.f);
        }
    }
    float pe[32];
#pragma unroll
    for (int c = 0; c < 32; c++) {
        float a = bpe[c];
#pragma unroll
        for (int i = 0; i < 12; i++) a += v[i] * wpe[i * 32 + c];
        pe[c] = fmaxf(a, 0.f);
    }
    float gd[32];
    {
        const bf16x8* g8 = (const bf16x8*)(gxb + (long)ind * 32);
#pragma unroll
        for (int c8 = 0; c8 < 4; c8++) {
            bf16x8 g = g8[c8];
#pragma unroll
            for (int e = 0; e < 8; e++) gd[c8 * 8 + e] = (float)g[e];
        }
    }
    float s1[8];
#pragma unroll
    for (int j = 0; j < 8; j++) s1[j] = bg1[j];
#pragma unroll
    for (int i = 0; i < 64; i++) {
        float gi = (i < 32) ? gd[i] : pe[i - 32];
        float sub = gi - rowmax16(gi);
#pragma unroll
        for (int j = 0; j < 8; j++) s1[j] += sub * wg1[i * 8 + j];
    }
#pragma unroll
    for (int j = 0; j < 8; j++) s1[j] = fmaxf(s1[j], 0.f);
    float s2[8];
#pragma unroll
    for (int j = 0; j < 8; j++) {
        float a = bg2[j];
#pragma unroll
        for (int i = 0; i < 8; i++) a += s1[i] * wg2[i * 8 + j];
        s2[j] = 1.f / (1.f + __expf(-a));
    }
    // nf = gathered fxb * headwise score; write in B-frag layout
    {
        const bf16x8* f8 = (const bf16x8*)(fxb + (long)ind * 32);
        int swz = (p & 3) << 4;
#pragma unroll
        for (int g = 0; g < 4; g++) {
            bf16x8 f = f8[g];
            float sA = s2[2 * g], sB = s2[2 * g + 1];
#pragma unroll
            for (int e = 0; e < 8; e++) {
                int c = g * 8 + e;
                float val = (float)f[e] * (e < 4 ? sA : sB);
                U.a.nfF[p * 512 + ((((c >> 4) * 256) + (c & 15) * 16 + q) ^ swz)] = (__bf16)val;
            }
        }
    }
    // shortcut maxpool over bf16 df rows
    {
        float4 mx = make_float4(-1e30f, -1e30f, -1e30f, -1e30f);
#pragma unroll
        for (int kk = 0; kk < 16; kk++) {
            int ik = sInd[p][kk];
            bf16x4 d = *(const bf16x4*)(dfb + (long)ik * 64 + q * 4);
            mx.x = fmaxf(mx.x, (float)d[0]); mx.y = fmaxf(mx.y, (float)d[1]);
            mx.z = fmaxf(mx.z, (float)d[2]); mx.w = fmaxf(mx.w, (float)d[3]);
        }
        bf16x4 pk;
        pk[0] = (__bf16)mx.x; pk[1] = (__bf16)mx.y; pk[2] = (__bf16)mx.z; pk[3] = (__bf16)mx.w;
        *(bf16x4*)(&sS[p][q * 4]) = pk;
    }

    // ---------------- phase 2 (MFMA): agg[j][c] per point ----------------
    {
        int wv2 = t >> 6, ln2 = t & 63;
        int col = ln2 & 15, quad = ln2 >> 4;
        bf16x8 z8 = {};
        bf16x4 dpk[4][2];
#pragma unroll
        for (int pp = 0; pp < 4; pp++) {
            int p2 = wv2 * 4 + pp;
            int swz = (p2 & 3) << 4;
            bf16x8 afr = z8, bf0 = z8, bf1 = z8;
            if (quad < 2) {
                afr = *(const bf16x8*)(&U.a.w3A[p2 * 256 + ((quad * 128 + col * 8) ^ swz)]);
                bf0 = *(const bf16x8*)(&U.a.nfF[p2 * 512 + ((col * 16 + quad * 8) ^ swz)]);
                bf1 = *(const bf16x8*)(&U.a.nfF[p2 * 512 + ((256 + col * 16 + quad * 8) ^ swz)]);
            }
            f32x4 ac0 = {0.f, 0.f, 0.f, 0.f}, ac1 = {0.f, 0.f, 0.f, 0.f};
            ac0 = __builtin_amdgcn_mfma_f32_16x16x32_bf16(afr, bf0, ac0, 0, 0, 0);
            ac1 = __builtin_amdgcn_mfma_f32_16x16x32_bf16(afr, bf1, ac1, 0, 0, 0);
#pragma unroll
            for (int r = 0; r < 4; r++) {
                dpk[pp][0][r] = (__bf16)ac0[r];
                dpk[pp][1][r] = (__bf16)ac1[r];
            }
        }
        __syncthreads();          // all frag reads done before aggB overwrite
#pragma unroll
        for (int pp = 0; pp < 4; pp++) {
            int p2 = wv2 * 4 + pp;
            *(bf16x4*)(&U.aggB[p2][col * 16 + quad * 4]) = dpk[pp][0];
            *(bf16x4*)(&U.aggB[p2][(16 + col) * 16 + quad * 4]) = dpk[pp][1];
        }
    }
    __syncthreads();

    // ---------------- phase 3: out64 = relu(agg @ wlin + blin), MFMA --------
    {
        int wv = t >> 6, ln = t & 63;
        int n = ln & 15, quad = ln >> 4;
        const __bf16* Bp = wlinT + ((wv * 16 + n) * 512 + quad * 8);
        f32x4 acc = {0.f, 0.f, 0.f, 0.f};
#pragma unroll
        for (int kk = 0; kk < 16; kk++) {
            bf16x8 a = *(const bf16x8*)(&U.aggB[n][kk * 32 + quad * 8]);
            bf16x8 b = *(const bf16x8*)(Bp + kk * 32);
            acc = __builtin_amdgcn_mfma_f32_16x16x32_bf16(a, b, acc, 0, 0, 0);
        }
        int col = wv * 16 + n;
        float bl = blin[col];
#pragma unroll
        for (int r = 0; r < 4; r++) {
            int row = quad * 4 + r;
            sO[row][col] = (__bf16)fmaxf(acc[r] + bl, 0.f);
        }
    }
    __syncthreads();

    // ---------------- phase 4: out = leaky(out64@wu2 + sf@wsc + b), MFMA ----
    {
        int wv = t >> 6, ln = t & 63;
        int n = ln & 15, quad = ln >> 4;
        bf16x8 aO0 = *(const bf16x8*)(&sO[n][quad * 8]);
        bf16x8 aO1 = *(const bf16x8*)(&sO[n][32 + quad * 8]);
        bf16x8 aS0 = *(const bf16x8*)(&sS[n][quad * 8]);
        bf16x8 aS1 = *(const bf16x8*)(&sS[n][32 + quad * 8]);
#pragma unroll
        for (int tt = 0; tt < 2; tt++) {
            int T = wv * 2 + tt;
            int col = T * 16 + n;
            const __bf16* B1 = wu2T + (col * 64 + quad * 8);
            const __bf16* B2 = wscT + (col * 64 + quad * 8);
            f32x4 acc = {0.f, 0.f, 0.f, 0.f};
            acc = __builtin_amdgcn_mfma_f32_16x16x32_bf16(aO0, *(const bf16x8*)(B1), acc, 0, 0, 0);
            acc = __builtin_amdgcn_mfma_f32_16x16x32_bf16(aO1, *(const bf16x8*)(B1 + 32), acc, 0, 0, 0);
            acc = __builtin_amdgcn_mfma_f32_16x16x32_bf16(aS0, *(const bf16x8*)(B2), acc, 0, 0, 0);
            acc = __builtin_amdgcn_mfma_f32_16x16x32_bf16(aS1, *(const bf16x8*)(B2 + 32), acc, 0, 0, 0);
            float bb = bu2[col] + bsc[col];
#pragma unroll
            for (int r = 0; r < 4; r++) {
                long mm = mbase + quad * 4 + r;
                if (mm < (long)M) {
                    float x = acc[r] + bb;
                    out[mm * 128 + col] = x > 0.f ? x : 0.1f * x;
                }
            }
        }
    }
}

extern "C" void kernel_launch(void* const* d_in, const int* in_sizes, int n_in,
                              void* d_out, int out_size, void* d_ws, size_t ws_size,
                              hipStream_t stream)
{
    const float* dense_feats = (const float*)d_in[1];
    const float* vi    = (const float*)d_in[5];
    const int*   nei   = (const int*)d_in[6];
    const float* w_u1  = (const float*)d_in[7];
    const float* b_u1  = (const float*)d_in[8];
    const float* w_gu  = (const float*)d_in[9];
    const float* b_gu  = (const float*)d_in[10];
    const float* w_pe  = (const float*)d_in[11];
    const float* b_pe  = (const float*)d_in[12];
    const float* w_g1  = (const float*)d_in[13];
    const float* b_g1  = (const float*)d_in[14];
    const float* w_g2  = (const float*)d_in[15];
    const float* b_g2  = (const float*)d_in[16];
    const float* w_wn1 = (const float*)d_in[17];
    const float* b_wn1 = (const float*)d_in[18];
    const float* w_wn2 = (const float*)d_in[19];
    const float* b_wn2 = (const float*)d_in[20];
    const float* w_wn3 = (const float*)d_in[21];
    const float* b_wn3 = (const float*)d_in[22];
    const float* w_lin = (const float*)d_in[23];
    const float* b_lin = (const float*)d_in[24];
    const float* w_u2  = (const float*)d_in[25];
    const float* b_u2  = (const float*)d_in[26];
    const float* w_sc  = (const float*)d_in[27];
    const float* b_sc  = (const float*)d_in[28];

    int N = in_sizes[1] / 64;     // 200000
    int M = in_sizes[6] / 16;     // 100000

    __bf16* fxb  = (__bf16*)d_ws;                        // [N,32] bf16
    __bf16* gxb  = fxb + (size_t)N * 32;                 // [N,32] bf16
    __bf16* dfb  = gxb + (size_t)N * 32;                 // [N,64] bf16
    __bf16* wlinT = dfb + (size_t)N * 64;                // [64,512]
    __bf16* wu2T  = wlinT + 64 * 512;                    // [128,64]
    __bf16* wscT  = wu2T + 128 * 64;                     // [128,64]
    __bf16* w1Th  = wscT + 128 * 64;                     // [32,64]
    __bf16* w1Tl  = w1Th + 32 * 64;                      // [32,64]
    __bf16* wgT   = w1Tl + 32 * 64;                      // [32,32]

    const int prep_items = 64 * 512 + 2 * 128 * 64 + 2 * 32 * 64 + 32 * 32;
    prep_kernel<<<(prep_items + 255) / 256, 256, 0, stream>>>(
        w_lin, w_u2, w_sc, w_u1, w_gu, wlinT, wu2T, wscT, w1Th, w1Tl, wgT);

    feats_kernel<<<(N + 63) / 64, 256, 0, stream>>>(
        dense_feats, w1Th, w1Tl, b_u1, wgT, b_gu, fxb, gxb, dfb, N);

    pcf_kernel<<<(M + 15) / 16, 256, 0, stream>>>(
        vi, nei, fxb, gxb, dfb,
        w_pe, b_pe, w_g1, b_g1, w_g2, b_g2,
        w_wn1, b_wn1, w_wn2, b_wn2, w_wn3, b_wn3,
        wlinT, b_lin, wu2T, b_u2, wscT, b_sc,
        (float*)d_out, M);
}

// Round 7
// 369.689 us; speedup vs baseline: 2.1563x; 1.0246x over previous
//
#include <hip/hip_runtime.h>
#include <math.h>

typedef __attribute__((ext_vector_type(8))) __bf16 bf16x8;
typedef __attribute__((ext_vector_type(4))) __bf16 bf16x4;
typedef __attribute__((ext_vector_type(4))) float f32x4;
typedef __attribute__((ext_vector_type(8))) unsigned short ushort8;
typedef __attribute__((ext_vector_type(2))) _Float16 h2;

__device__ __forceinline__ float fdot2(h2 a, h2 b, float c) {
#if __has_builtin(__builtin_amdgcn_fdot2)
    return __builtin_amdgcn_fdot2(a, b, c, false);
#else
    return c + (float)a[0] * (float)b[0] + (float)a[1] * (float)b[1];
#endif
}

__device__ __forceinline__ h2 h2max(h2 a, h2 b) {
#if __has_builtin(__builtin_elementwise_max)
    return __builtin_elementwise_max(a, b);
#else
    h2 r; r[0] = a[0] > b[0] ? a[0] : b[0]; r[1] = a[1] > b[1] ? a[1] : b[1]; return r;
#endif
}

// packed-pair max over the 16-lane group via DPP row rotations
__device__ __forceinline__ h2 rowmax16h(h2 x) {
    int xi = __builtin_bit_cast(int, x);
    int y;
    y = __builtin_amdgcn_update_dpp(0, xi, 0x128, 0xf, 0xf, true); // ror:8
    x = h2max(x, __builtin_bit_cast(h2, y)); xi = __builtin_bit_cast(int, x);
    y = __builtin_amdgcn_update_dpp(0, xi, 0x124, 0xf, 0xf, true); // ror:4
    x = h2max(x, __builtin_bit_cast(h2, y)); xi = __builtin_bit_cast(int, x);
    y = __builtin_amdgcn_update_dpp(0, xi, 0x122, 0xf, 0xf, true); // ror:2
    x = h2max(x, __builtin_bit_cast(h2, y)); xi = __builtin_bit_cast(int, x);
    y = __builtin_amdgcn_update_dpp(0, xi, 0x121, 0xf, 0xf, true); // ror:1
    x = h2max(x, __builtin_bit_cast(h2, y));
    return x;
}

__device__ __forceinline__ unsigned int packh2(float a, float b) {
    h2 v = { (_Float16)a, (_Float16)b };
    return __builtin_bit_cast(unsigned int, v);
}

// ---------------------------------------------------------------------------
// prep: bf16 transposes for epilogue weights + hi/lo split feats weights +
// f16-pair-packed small-net weights (for v_dot2_f32_f16 chains in pcf).
// ---------------------------------------------------------------------------
__global__ void prep_kernel(const float* __restrict__ wlin,
                            const float* __restrict__ wu2,
                            const float* __restrict__ wsc,
                            const float* __restrict__ w1,
                            const float* __restrict__ wg,
                            const float* __restrict__ wg1,
                            const float* __restrict__ wpe,
                            const float* __restrict__ wn1,
                            const float* __restrict__ wn2,
                            const float* __restrict__ wn3,
                            const float* __restrict__ wg2,
                            __bf16* __restrict__ wlinT,
                            __bf16* __restrict__ wu2T,
                            __bf16* __restrict__ wscT,
                            __bf16* __restrict__ w1Th,
                            __bf16* __restrict__ w1Tl,
                            __bf16* __restrict__ wgT,
                            unsigned int* __restrict__ pk)   // packed block
{
    const int B0 = 64 * 512;              // wlinT
    const int B1 = B0 + 128 * 64;         // wu2T
    const int B2 = B1 + 128 * 64;         // wscT
    const int B3 = B2 + 32 * 64;          // w1Th/l
    const int B4 = B3 + 32 * 32;          // wgT
    const int B5 = B4 + 256;              // wg1P [32t][8j]
    const int B6 = B5 + 192;              // wpeP [6t][32c]
    const int B7 = B6 + 48;               // wn1P [6t][8j]
    const int B8 = B7 + 32;               // wn2P [4t][8j]
    const int B9 = B8 + 64;               // wn3P [4t][16j]
    const int B10 = B9 + 32;              // wg2P [4t][8j]
    int i = blockIdx.x * 256 + threadIdx.x;
    if (i < B0) {
        int l = i >> 9, k = i & 511;
        wlinT[i] = (__bf16)wlin[k * 64 + l];
    } else if (i < B1) {
        int j = i - B0; int co = j >> 6, kk = j & 63;
        wu2T[j] = (__bf16)wu2[kk * 128 + co];
    } else if (i < B2) {
        int j = i - B1; int co = j >> 6, kk = j & 63;
        wscT[j] = (__bf16)wsc[kk * 128 + co];
    } else if (i < B3) {
        int j = i - B2; int c = j >> 6, k = j & 63;
        float v = w1[k * 32 + c];
        __bf16 h = (__bf16)v;
        w1Th[j] = h;
        w1Tl[j] = (__bf16)(v - (float)h);
    } else if (i < B4) {
        int j = i - B3; int c = j >> 5, k = j & 31;
        wgT[j] = (__bf16)wg[k * 32 + c];
    } else if (i < B5) {
        int j2 = i - B4; int t = j2 >> 3, j = j2 & 7;
        pk[j2] = packh2(wg1[(2 * t) * 8 + j], wg1[(2 * t + 1) * 8 + j]);
    } else if (i < B6) {
        int j2 = i - B5; int t = j2 >> 5, c = j2 & 31;
        pk[256 + j2] = packh2(wpe[(2 * t) * 32 + c], wpe[(2 * t + 1) * 32 + c]);
    } else if (i < B7) {
        int j2 = i - B6; int t = j2 >> 3, j = j2 & 7;
        pk[448 + j2] = packh2(wn1[(2 * t) * 8 + j], wn1[(2 * t + 1) * 8 + j]);
    } else if (i < B8) {
        int j2 = i - B7; int t = j2 >> 3, j = j2 & 7;
        pk[496 + j2] = packh2(wn2[(2 * t) * 8 + j], wn2[(2 * t + 1) * 8 + j]);
    } else if (i < B9) {
        int j2 = i - B8; int t = j2 >> 4, j = j2 & 15;
        pk[528 + j2] = packh2(wn3[(2 * t) * 16 + j], wn3[(2 * t + 1) * 16 + j]);
    } else if (i < B10) {
        int j2 = i - B9; int t = j2 >> 3, j = j2 & 7;
        pk[592 + j2] = packh2(wg2[(2 * t) * 8 + j], wg2[(2 * t + 1) * 8 + j]);
    }
}

// ---------------------------------------------------------------------------
// Kernel A: MFMA feats. gx now stored as packed f16 (consumed by fdot2 in
// pcf with zero unpack cost). fx bf16, dfb bf16 as before.
// ---------------------------------------------------------------------------
__global__ __launch_bounds__(256) void feats_kernel(
    const float* __restrict__ df,
    const __bf16* __restrict__ w1Th, const __bf16* __restrict__ w1Tl,
    const float* __restrict__ b1,
    const __bf16* __restrict__ wgT, const float* __restrict__ bg,
    __bf16* __restrict__ fxb, unsigned short* __restrict__ gxh,
    __bf16* __restrict__ dfb, int N)
{
    __shared__ unsigned short sFx[4][16][40];  // per-wave tile, padded rows
    int t = threadIdx.x;
    int wv = t >> 6, ln = t & 63;
    int row = ln & 15, quad = ln >> 4;
    long n0 = (long)blockIdx.x * 64 + wv * 16;
    long n = n0 + row;
    bool ok = n < (long)N;

    // ---- load df row fragment
    const float4* dp = (const float4*)(df + (ok ? n * 64 : 0));
    float4 f00 = dp[quad * 2 + 0], f01 = dp[quad * 2 + 1];
    float4 f10 = dp[8 + quad * 2 + 0], f11 = dp[8 + quad * 2 + 1];
    float s0[8] = {f00.x, f00.y, f00.z, f00.w, f01.x, f01.y, f01.z, f01.w};
    float s1[8] = {f10.x, f10.y, f10.z, f10.w, f11.x, f11.y, f11.z, f11.w};
    bf16x8 aH0, aL0, aH1, aL1;
#pragma unroll
    for (int e = 0; e < 8; e++) {
        __bf16 h = (__bf16)s0[e]; aH0[e] = h; aL0[e] = (__bf16)(s0[e] - (float)h);
        __bf16 g = (__bf16)s1[e]; aH1[e] = g; aL1[e] = (__bf16)(s1[e] - (float)g);
    }
    if (ok) {
        *(bf16x8*)(dfb + n * 64 + quad * 8) = aH0;
        *(bf16x8*)(dfb + n * 64 + 32 + quad * 8) = aH1;
    }

    // ---- GEMM1: fx = leaky(df @ w1 + b1), split-precision MFMA
    const __bf16* bh = w1Th + (row * 64 + quad * 8);
    const __bf16* bl = w1Tl + (row * 64 + quad * 8);
    f32x4 acc0 = {0.f, 0.f, 0.f, 0.f}, acc1 = {0.f, 0.f, 0.f, 0.f};
    {
        bf16x8 bH00 = *(const bf16x8*)(bh);
        bf16x8 bH01 = *(const bf16x8*)(bh + 32);
        bf16x8 bH10 = *(const bf16x8*)(bh + 16 * 64);
        bf16x8 bH11 = *(const bf16x8*)(bh + 16 * 64 + 32);
        bf16x8 bL00 = *(const bf16x8*)(bl);
        bf16x8 bL01 = *(const bf16x8*)(bl + 32);
        bf16x8 bL10 = *(const bf16x8*)(bl + 16 * 64);
        bf16x8 bL11 = *(const bf16x8*)(bl + 16 * 64 + 32);
        acc0 = __builtin_amdgcn_mfma_f32_16x16x32_bf16(aH0, bH00, acc0, 0, 0, 0);
        acc0 = __builtin_amdgcn_mfma_f32_16x16x32_bf16(aH1, bH01, acc0, 0, 0, 0);
        acc0 = __builtin_amdgcn_mfma_f32_16x16x32_bf16(aL0, bH00, acc0, 0, 0, 0);
        acc0 = __builtin_amdgcn_mfma_f32_16x16x32_bf16(aL1, bH01, acc0, 0, 0, 0);
        acc0 = __builtin_amdgcn_mfma_f32_16x16x32_bf16(aH0, bL00, acc0, 0, 0, 0);
        acc0 = __builtin_amdgcn_mfma_f32_16x16x32_bf16(aH1, bL01, acc0, 0, 0, 0);
        acc1 = __builtin_amdgcn_mfma_f32_16x16x32_bf16(aH0, bH10, acc1, 0, 0, 0);
        acc1 = __builtin_amdgcn_mfma_f32_16x16x32_bf16(aH1, bH11, acc1, 0, 0, 0);
        acc1 = __builtin_amdgcn_mfma_f32_16x16x32_bf16(aL0, bH10, acc1, 0, 0, 0);
        acc1 = __builtin_amdgcn_mfma_f32_16x16x32_bf16(aL1, bH11, acc1, 0, 0, 0);
        acc1 = __builtin_amdgcn_mfma_f32_16x16x32_bf16(aH0, bL10, acc1, 0, 0, 0);
        acc1 = __builtin_amdgcn_mfma_f32_16x16x32_bf16(aH1, bL11, acc1, 0, 0, 0);
    }
    // epilogue -> sFx (bf16 bits)
    {
        float bb0 = b1[row], bb1 = b1[16 + row];
#pragma unroll
        for (int r = 0; r < 4; r++) {
            float x0 = acc0[r] + bb0; x0 = x0 > 0.f ? x0 : 0.1f * x0;
            float x1 = acc1[r] + bb1; x1 = x1 > 0.f ? x1 : 0.1f * x1;
            sFx[wv][quad * 4 + r][row] = __builtin_bit_cast(unsigned short, (__bf16)x0);
            sFx[wv][quad * 4 + r][16 + row] = __builtin_bit_cast(unsigned short, (__bf16)x1);
        }
    }
    __builtin_amdgcn_s_waitcnt(0);   // own-wave LDS handoff

    // ---- GEMM2: gx = fx @ wg + bg (bf16 MFMA)
    f32x4 g0 = {0.f, 0.f, 0.f, 0.f}, g1 = {0.f, 0.f, 0.f, 0.f};
    {
        bf16x8 a2 = __builtin_bit_cast(bf16x8, *(const ushort8*)(&sFx[wv][row][quad * 8]));
        bf16x8 b20 = *(const bf16x8*)(wgT + row * 32 + quad * 8);
        bf16x8 b21 = *(const bf16x8*)(wgT + (16 + row) * 32 + quad * 8);
        g0 = __builtin_amdgcn_mfma_f32_16x16x32_bf16(a2, b20, g0, 0, 0, 0);
        g1 = __builtin_amdgcn_mfma_f32_16x16x32_bf16(a2, b21, g1, 0, 0, 0);
    }
    // ---- coalesced fxb store (reads sFx before overwrite)
    {
        int r16 = ln >> 2, seg = ln & 3;
        ushort8 vfx = *(const ushort8*)(&sFx[wv][r16][seg * 8]);
        long nn = n0 + r16;
        if (nn < (long)N) *(ushort8*)((unsigned short*)fxb + nn * 32 + seg * 8) = vfx;
    }
    // ---- overwrite sFx with g-tile (f16 bits), then coalesced gxh store
    {
        float bb0 = bg[row], bb1 = bg[16 + row];
#pragma unroll
        for (int r = 0; r < 4; r++) {
            sFx[wv][quad * 4 + r][row] = __builtin_bit_cast(unsigned short, (_Float16)(g0[r] + bb0));
            sFx[wv][quad * 4 + r][16 + row] = __builtin_bit_cast(unsigned short, (_Float16)(g1[r] + bb1));
        }
    }
    __builtin_amdgcn_s_waitcnt(0);
    {
        int r16 = ln >> 2, seg = ln & 3;
        ushort8 vg = *(const ushort8*)(&sFx[wv][r16][seg * 8]);
        long nn = n0 + r16;
        if (nn < (long)N) *(ushort8*)(gxh + nn * 32 + seg * 8) = vg;
    }
}

// ---------------------------------------------------------------------------
// Kernel B v6: phase-1 small-net chains converted to f16 dot2 (v_dot2_f32_f16,
// 2 MAC/inst) + packed rowmax (DPP + v_pk_max_f16). Halves the three dominant
// VALU chains (guidance 1100->~550, pe 420->~270, weightnet 350->~180) and
// removes the gd unpack (gx stored packed f16). Phases 2-4 unchanged from v5.
// ---------------------------------------------------------------------------
struct SmemU {
    union {
        struct { __bf16 nfF[16 * 512]; __bf16 w3A[16 * 256]; } a; // 24576 B
        __bf16 aggB[16][520];                                     // 16640 B
    };
};

__global__ __launch_bounds__(256, 5) void pcf_kernel(
    const float* __restrict__ vi, const int* __restrict__ nei,
    const __bf16* __restrict__ fxb, const unsigned short* __restrict__ gxh,
    const __bf16* __restrict__ dfb,
    const unsigned int* __restrict__ pk,    // packed f16-pair weights
    const float* __restrict__ bpe,
    const float* __restrict__ bg1, const float* __restrict__ bg2,
    const float* __restrict__ bn1, const float* __restrict__ bn2,
    const float* __restrict__ bn3,
    const __bf16* __restrict__ wlinT, const float* __restrict__ blin,
    const __bf16* __restrict__ wu2T, const float* __restrict__ bu2,
    const __bf16* __restrict__ wscT, const float* __restrict__ bsc,
    float* __restrict__ out, int M)
{
    __shared__ SmemU U;
    __shared__ __bf16 sO[16][72];     // out64, padded rows
    __shared__ __bf16 sS[16][72];     // shortcut maxpool
    __shared__ int sInd[16][16];

    const unsigned int* wg1P = pk;          // [32t][8j]
    const unsigned int* wpeP = pk + 256;    // [6t][32c]
    const unsigned int* wn1P = pk + 448;    // [6t][8j]
    const unsigned int* wn2P = pk + 496;    // [4t][8j]
    const unsigned int* wn3P = pk + 528;    // [4t][16j]
    const unsigned int* wg2P = pk + 592;    // [4t][8j]

    int t = threadIdx.x;
    int p = t >> 4, q = t & 15;
    long mbase = (long)blockIdx.x * 16;
    long m = mbase + p;
    bool okm = m < (long)M;
    int ind = okm ? nei[m * 16 + q] : 0;
    sInd[p][q] = ind;

    // ---------------- phase 1 ----------------
    h2 vh[6];
    {
        const float4* v4 = (const float4*)(vi + (okm ? (m * 16 + q) * 12 : 0));
        float4 a = v4[0], b = v4[1], cc = v4[2];
        vh[0] = (h2){(_Float16)a.x, (_Float16)a.y};
        vh[1] = (h2){(_Float16)a.z, (_Float16)a.w};
        vh[2] = (h2){(_Float16)b.x, (_Float16)b.y};
        vh[3] = (h2){(_Float16)b.z, (_Float16)b.w};
        vh[4] = (h2){(_Float16)cc.x, (_Float16)cc.y};
        vh[5] = (h2){(_Float16)cc.z, (_Float16)cc.w};
    }
    // weightnet chain (dot2); write w3 in A-frag layout
    {
        float wa[8];
#pragma unroll
        for (int j = 0; j < 8; j++) {
            float a = bn1[j];
#pragma unroll
            for (int tt2 = 0; tt2 < 6; tt2++)
                a = fdot2(vh[tt2], __builtin_bit_cast(h2, wn1P[tt2 * 8 + j]), a);
            wa[j] = fmaxf(a, 0.f);
        }
        h2 wah[4];
#pragma unroll
        for (int tt2 = 0; tt2 < 4; tt2++)
            wah[tt2] = (h2){(_Float16)wa[2 * tt2], (_Float16)wa[2 * tt2 + 1]};
        float wb[8];
#pragma unroll
        for (int j = 0; j < 8; j++) {
            float a = bn2[j];
#pragma unroll
            for (int tt2 = 0; tt2 < 4; tt2++)
                a = fdot2(wah[tt2], __builtin_bit_cast(h2, wn2P[tt2 * 8 + j]), a);
            wb[j] = fmaxf(a, 0.f);
        }
        h2 wbh[4];
#pragma unroll
        for (int tt2 = 0; tt2 < 4; tt2++)
            wbh[tt2] = (h2){(_Float16)wb[2 * tt2], (_Float16)wb[2 * tt2 + 1]};
        int swz = (p & 3) << 4;
        int kb = (q >> 3) * 128 + (q & 7);
#pragma unroll
        for (int j = 0; j < 16; j++) {
            float a = bn3[j];
#pragma unroll
            for (int tt2 = 0; tt2 < 4; tt2++)
                a = fdot2(wbh[tt2], __builtin_bit_cast(h2, wn3P[tt2 * 16 + j]), a);
            U.a.w3A[p * 256 + ((kb + j * 8) ^ swz)] = (__bf16)fmaxf(a, 0.f);
        }
    }
    // pe = relu(vi@wpe + bpe), packed into pairs
    h2 peh[16];
#pragma unroll
    for (int c2 = 0; c2 < 16; c2++) {
        float a0 = bpe[2 * c2], a1 = bpe[2 * c2 + 1];
#pragma unroll
        for (int tt2 = 0; tt2 < 6; tt2++) {
            a0 = fdot2(vh[tt2], __builtin_bit_cast(h2, wpeP[tt2 * 32 + 2 * c2]), a0);
            a1 = fdot2(vh[tt2], __builtin_bit_cast(h2, wpeP[tt2 * 32 + 2 * c2 + 1]), a1);
        }
        peh[c2] = (h2){(_Float16)fmaxf(a0, 0.f), (_Float16)fmaxf(a1, 0.f)};
    }
    // gathered guidance row (packed f16, zero unpack)
    h2 gdh[16];
    {
        const unsigned int* gu = (const unsigned int*)(gxh + (long)ind * 32);
#pragma unroll
        for (int tt2 = 0; tt2 < 16; tt2++)
            gdh[tt2] = __builtin_bit_cast(h2, gu[tt2]);
    }
    // guidance: s1[j] = sum_t dot2(g2 - rowmax(g2), wg1P[t][j])
    float s1[8];
#pragma unroll
    for (int j = 0; j < 8; j++) s1[j] = bg1[j];
#pragma unroll
    for (int tt2 = 0; tt2 < 32; tt2++) {
        h2 g2 = (tt2 < 16) ? gdh[tt2] : peh[tt2 - 16];
        h2 m2 = rowmax16h(g2);
        h2 sub = g2 - m2;
#pragma unroll
        for (int j = 0; j < 8; j++)
            s1[j] = fdot2(sub, __builtin_bit_cast(h2, wg1P[tt2 * 8 + j]), s1[j]);
    }
    h2 s1h[4];
#pragma unroll
    for (int tt2 = 0; tt2 < 4; tt2++)
        s1h[tt2] = (h2){(_Float16)fmaxf(s1[2 * tt2], 0.f), (_Float16)fmaxf(s1[2 * tt2 + 1], 0.f)};
    float s2[8];
#pragma unroll
    for (int j = 0; j < 8; j++) {
        float a = bg2[j];
#pragma unroll
        for (int tt2 = 0; tt2 < 4; tt2++)
            a = fdot2(s1h[tt2], __builtin_bit_cast(h2, wg2P[tt2 * 8 + j]), a);
        s2[j] = 1.f / (1.f + __expf(-a));
    }
    // nf = gathered fxb * headwise score; write in B-frag layout
    {
        const bf16x8* f8 = (const bf16x8*)(fxb + (long)ind * 32);
        int swz = (p & 3) << 4;
#pragma unroll
        for (int g = 0; g < 4; g++) {
            bf16x8 f = f8[g];
            float sA = s2[2 * g], sB = s2[2 * g + 1];
#pragma unroll
            for (int e = 0; e < 8; e++) {
                int c = g * 8 + e;
                float val = (float)f[e] * (e < 4 ? sA : sB);
                U.a.nfF[p * 512 + ((((c >> 4) * 256) + (c & 15) * 16 + q) ^ swz)] = (__bf16)val;
            }
        }
    }
    // shortcut maxpool over bf16 df rows
    {
        float4 mx = make_float4(-1e30f, -1e30f, -1e30f, -1e30f);
#pragma unroll
        for (int kk = 0; kk < 16; kk++) {
            int ik = sInd[p][kk];
            bf16x4 d = *(const bf16x4*)(dfb + (long)ik * 64 + q * 4);
            mx.x = fmaxf(mx.x, (float)d[0]); mx.y = fmaxf(mx.y, (float)d[1]);
            mx.z = fmaxf(mx.z, (float)d[2]); mx.w = fmaxf(mx.w, (float)d[3]);
        }
        bf16x4 pkk;
        pkk[0] = (__bf16)mx.x; pkk[1] = (__bf16)mx.y; pkk[2] = (__bf16)mx.z; pkk[3] = (__bf16)mx.w;
        *(bf16x4*)(&sS[p][q * 4]) = pkk;
    }

    // ---------------- phase 2 (MFMA): agg[j][c] per point ----------------
    {
        int wv2 = t >> 6, ln2 = t & 63;
        int col = ln2 & 15, quad = ln2 >> 4;
        bf16x8 z8 = {};
        bf16x4 dpk[4][2];
#pragma unroll
        for (int pp = 0; pp < 4; pp++) {
            int p2 = wv2 * 4 + pp;
            int swz = (p2 & 3) << 4;
            bf16x8 afr = z8, bf0 = z8, bf1 = z8;
            if (quad < 2) {
                afr = *(const bf16x8*)(&U.a.w3A[p2 * 256 + ((quad * 128 + col * 8) ^ swz)]);
                bf0 = *(const bf16x8*)(&U.a.nfF[p2 * 512 + ((col * 16 + quad * 8) ^ swz)]);
                bf1 = *(const bf16x8*)(&U.a.nfF[p2 * 512 + ((256 + col * 16 + quad * 8) ^ swz)]);
            }
            f32x4 ac0 = {0.f, 0.f, 0.f, 0.f}, ac1 = {0.f, 0.f, 0.f, 0.f};
            ac0 = __builtin_amdgcn_mfma_f32_16x16x32_bf16(afr, bf0, ac0, 0, 0, 0);
            ac1 = __builtin_amdgcn_mfma_f32_16x16x32_bf16(afr, bf1, ac1, 0, 0, 0);
#pragma unroll
            for (int r = 0; r < 4; r++) {
                dpk[pp][0][r] = (__bf16)ac0[r];
                dpk[pp][1][r] = (__bf16)ac1[r];
            }
        }
        __syncthreads();          // all frag reads done before aggB overwrite
#pragma unroll
        for (int pp = 0; pp < 4; pp++) {
            int p2 = wv2 * 4 + pp;
            *(bf16x4*)(&U.aggB[p2][col * 16 + quad * 4]) = dpk[pp][0];
            *(bf16x4*)(&U.aggB[p2][(16 + col) * 16 + quad * 4]) = dpk[pp][1];
        }
    }
    __syncthreads();

    // ---------------- phase 3: out64 = relu(agg @ wlin + blin), MFMA --------
    {
        int wv = t >> 6, ln = t & 63;
        int n = ln & 15, quad = ln >> 4;
        const __bf16* Bp = wlinT + ((wv * 16 + n) * 512 + quad * 8);
        f32x4 acc = {0.f, 0.f, 0.f, 0.f};
#pragma unroll
        for (int kk = 0; kk < 16; kk++) {
            bf16x8 a = *(const bf16x8*)(&U.aggB[n][kk * 32 + quad * 8]);
            bf16x8 b = *(const bf16x8*)(Bp + kk * 32);
            acc = __builtin_amdgcn_mfma_f32_16x16x32_bf16(a, b, acc, 0, 0, 0);
        }
        int col = wv * 16 + n;
        float bl = blin[col];
#pragma unroll
        for (int r = 0; r < 4; r++) {
            int row = quad * 4 + r;
            sO[row][col] = (__bf16)fmaxf(acc[r] + bl, 0.f);
        }
    }
    __syncthreads();

    // ---------------- phase 4: out = leaky(out64@wu2 + sf@wsc + b), MFMA ----
    {
        int wv = t >> 6, ln = t & 63;
        int n = ln & 15, quad = ln >> 4;
        bf16x8 aO0 = *(const bf16x8*)(&sO[n][quad * 8]);
        bf16x8 aO1 = *(const bf16x8*)(&sO[n][32 + quad * 8]);
        bf16x8 aS0 = *(const bf16x8*)(&sS[n][quad * 8]);
        bf16x8 aS1 = *(const bf16x8*)(&sS[n][32 + quad * 8]);
#pragma unroll
        for (int tt = 0; tt < 2; tt++) {
            int T = wv * 2 + tt;
            int col = T * 16 + n;
            const __bf16* B1 = wu2T + (col * 64 + quad * 8);
            const __bf16* B2 = wscT + (col * 64 + quad * 8);
            f32x4 acc = {0.f, 0.f, 0.f, 0.f};
            acc = __builtin_amdgcn_mfma_f32_16x16x32_bf16(aO0, *(const bf16x8*)(B1), acc, 0, 0, 0);
            acc = __builtin_amdgcn_mfma_f32_16x16x32_bf16(aO1, *(const bf16x8*)(B1 + 32), acc, 0, 0, 0);
            acc = __builtin_amdgcn_mfma_f32_16x16x32_bf16(aS0, *(const bf16x8*)(B2), acc, 0, 0, 0);
            acc = __builtin_amdgcn_mfma_f32_16x16x32_bf16(aS1, *(const bf16x8*)(B2 + 32), acc, 0, 0, 0);
            float bb = bu2[col] + bsc[col];
#pragma unroll
            for (int r = 0; r < 4; r++) {
                long mm = mbase + quad * 4 + r;
                if (mm < (long)M) {
                    float x = acc[r] + bb;
                    out[mm * 128 + col] = x > 0.f ? x : 0.1f * x;
                }
            }
        }
    }
}

extern "C" void kernel_launch(void* const* d_in, const int* in_sizes, int n_in,
                              void* d_out, int out_size, void* d_ws, size_t ws_size,
                              hipStream_t stream)
{
    const float* dense_feats = (const float*)d_in[1];
    const float* vi    = (const float*)d_in[5];
    const int*   nei   = (const int*)d_in[6];
    const float* w_u1  = (const float*)d_in[7];
    const float* b_u1  = (const float*)d_in[8];
    const float* w_gu  = (const float*)d_in[9];
    const float* b_gu  = (const float*)d_in[10];
    const float* w_pe  = (const float*)d_in[11];
    const float* b_pe  = (const float*)d_in[12];
    const float* w_g1  = (const float*)d_in[13];
    const float* b_g1  = (const float*)d_in[14];
    const float* w_g2  = (const float*)d_in[15];
    const float* b_g2  = (const float*)d_in[16];
    const float* w_wn1 = (const float*)d_in[17];
    const float* b_wn1 = (const float*)d_in[18];
    const float* w_wn2 = (const float*)d_in[19];
    const float* b_wn2 = (const float*)d_in[20];
    const float* w_wn3 = (const float*)d_in[21];
    const float* b_wn3 = (const float*)d_in[22];
    const float* w_lin = (const float*)d_in[23];
    const float* b_lin = (const float*)d_in[24];
    const float* w_u2  = (const float*)d_in[25];
    const float* b_u2  = (const float*)d_in[26];
    const float* w_sc  = (const float*)d_in[27];
    const float* b_sc  = (const float*)d_in[28];

    int N = in_sizes[1] / 64;     // 200000
    int M = in_sizes[6] / 16;     // 100000

    __bf16* fxb  = (__bf16*)d_ws;                        // [N,32] bf16
    unsigned short* gxh = (unsigned short*)(fxb + (size_t)N * 32); // [N,32] f16
    __bf16* dfb  = (__bf16*)(gxh + (size_t)N * 32);      // [N,64] bf16
    __bf16* wlinT = dfb + (size_t)N * 64;                // [64,512]
    __bf16* wu2T  = wlinT + 64 * 512;                    // [128,64]
    __bf16* wscT  = wu2T + 128 * 64;                     // [128,64]
    __bf16* w1Th  = wscT + 128 * 64;                     // [32,64]
    __bf16* w1Tl  = w1Th + 32 * 64;                      // [32,64]
    __bf16* wgT   = w1Tl + 32 * 64;                      // [32,32]
    unsigned int* pk = (unsigned int*)(wgT + 32 * 32);   // 624 packed uints

    const int prep_items = 64 * 512 + 2 * 128 * 64 + 2 * 32 * 64 + 32 * 32 + 624;
    prep_kernel<<<(prep_items + 255) / 256, 256, 0, stream>>>(
        w_lin, w_u2, w_sc, w_u1, w_gu, w_g1, w_pe, w_wn1, w_wn2, w_wn3, w_g2,
        wlinT, wu2T, wscT, w1Th, w1Tl, wgT, pk);

    feats_kernel<<<(N + 63) / 64, 256, 0, stream>>>(
        dense_feats, w1Th, w1Tl, b_u1, wgT, b_gu, fxb, gxh, dfb, N);

    pcf_kernel<<<(M + 15) / 16, 256, 0, stream>>>(
        vi, nei, fxb, gxh, dfb, pk,
        b_pe, b_g1, b_g2, b_wn1, b_wn2, b_wn3,
        wlinT, b_lin, wu2T, b_u2, wscT, b_sc,
        (float*)d_out, M);
}

// Round 8
// 350.451 us; speedup vs baseline: 2.2747x; 1.0549x over previous
//
#include <hip/hip_runtime.h>
#include <math.h>

typedef __attribute__((ext_vector_type(8))) __bf16 bf16x8;
typedef __attribute__((ext_vector_type(4))) __bf16 bf16x4;
typedef __attribute__((ext_vector_type(4))) float f32x4;
typedef __attribute__((ext_vector_type(8))) unsigned short ushort8;
typedef __attribute__((ext_vector_type(2))) _Float16 h2;

__device__ __forceinline__ float fdot2(h2 a, h2 b, float c) {
#if __has_builtin(__builtin_amdgcn_fdot2)
    return __builtin_amdgcn_fdot2(a, b, c, false);
#else
    return c + (float)a[0] * (float)b[0] + (float)a[1] * (float)b[1];
#endif
}

__device__ __forceinline__ h2 h2max(h2 a, h2 b) {
#if __has_builtin(__builtin_elementwise_max)
    return __builtin_elementwise_max(a, b);
#else
    h2 r; r[0] = a[0] > b[0] ? a[0] : b[0]; r[1] = a[1] > b[1] ? a[1] : b[1]; return r;
#endif
}

// packed-pair max over the 16-lane group via DPP row rotations
__device__ __forceinline__ h2 rowmax16h(h2 x) {
    int xi = __builtin_bit_cast(int, x);
    int y;
    y = __builtin_amdgcn_update_dpp(0, xi, 0x128, 0xf, 0xf, true); // ror:8
    x = h2max(x, __builtin_bit_cast(h2, y)); xi = __builtin_bit_cast(int, x);
    y = __builtin_amdgcn_update_dpp(0, xi, 0x124, 0xf, 0xf, true); // ror:4
    x = h2max(x, __builtin_bit_cast(h2, y)); xi = __builtin_bit_cast(int, x);
    y = __builtin_amdgcn_update_dpp(0, xi, 0x122, 0xf, 0xf, true); // ror:2
    x = h2max(x, __builtin_bit_cast(h2, y)); xi = __builtin_bit_cast(int, x);
    y = __builtin_amdgcn_update_dpp(0, xi, 0x121, 0xf, 0xf, true); // ror:1
    x = h2max(x, __builtin_bit_cast(h2, y));
    return x;
}

__device__ __forceinline__ unsigned int packh2(float a, float b) {
    h2 v = { (_Float16)a, (_Float16)b };
    return __builtin_bit_cast(unsigned int, v);
}

// ---------------------------------------------------------------------------
// prep: bf16 transposes for epilogue weights + hi/lo split feats weights +
// f16-pair-packed small-net weights (for v_dot2_f32_f16 chains in pcf).
// ---------------------------------------------------------------------------
__global__ void prep_kernel(const float* __restrict__ wlin,
                            const float* __restrict__ wu2,
                            const float* __restrict__ wsc,
                            const float* __restrict__ w1,
                            const float* __restrict__ wg,
                            const float* __restrict__ wg1,
                            const float* __restrict__ wpe,
                            const float* __restrict__ wn1,
                            const float* __restrict__ wn2,
                            const float* __restrict__ wn3,
                            const float* __restrict__ wg2,
                            __bf16* __restrict__ wlinT,
                            __bf16* __restrict__ wu2T,
                            __bf16* __restrict__ wscT,
                            __bf16* __restrict__ w1Th,
                            __bf16* __restrict__ w1Tl,
                            __bf16* __restrict__ wgT,
                            unsigned int* __restrict__ pk)   // packed block
{
    const int B0 = 64 * 512;              // wlinT
    const int B1 = B0 + 128 * 64;         // wu2T
    const int B2 = B1 + 128 * 64;         // wscT
    const int B3 = B2 + 32 * 64;          // w1Th/l
    const int B4 = B3 + 32 * 32;          // wgT
    const int B5 = B4 + 256;              // wg1P [32t][8j]
    const int B6 = B5 + 192;              // wpeP [6t][32c]
    const int B7 = B6 + 48;               // wn1P [6t][8j]
    const int B8 = B7 + 32;               // wn2P [4t][8j]
    const int B9 = B8 + 64;               // wn3P [4t][16j]
    const int B10 = B9 + 32;              // wg2P [4t][8j]
    int i = blockIdx.x * 256 + threadIdx.x;
    if (i < B0) {
        int l = i >> 9, k = i & 511;
        wlinT[i] = (__bf16)wlin[k * 64 + l];
    } else if (i < B1) {
        int j = i - B0; int co = j >> 6, kk = j & 63;
        wu2T[j] = (__bf16)wu2[kk * 128 + co];
    } else if (i < B2) {
        int j = i - B1; int co = j >> 6, kk = j & 63;
        wscT[j] = (__bf16)wsc[kk * 128 + co];
    } else if (i < B3) {
        int j = i - B2; int c = j >> 6, k = j & 63;
        float v = w1[k * 32 + c];
        __bf16 h = (__bf16)v;
        w1Th[j] = h;
        w1Tl[j] = (__bf16)(v - (float)h);
    } else if (i < B4) {
        int j = i - B3; int c = j >> 5, k = j & 31;
        wgT[j] = (__bf16)wg[k * 32 + c];
    } else if (i < B5) {
        int j2 = i - B4; int t = j2 >> 3, j = j2 & 7;
        pk[j2] = packh2(wg1[(2 * t) * 8 + j], wg1[(2 * t + 1) * 8 + j]);
    } else if (i < B6) {
        int j2 = i - B5; int t = j2 >> 5, c = j2 & 31;
        pk[256 + j2] = packh2(wpe[(2 * t) * 32 + c], wpe[(2 * t + 1) * 32 + c]);
    } else if (i < B7) {
        int j2 = i - B6; int t = j2 >> 3, j = j2 & 7;
        pk[448 + j2] = packh2(wn1[(2 * t) * 8 + j], wn1[(2 * t + 1) * 8 + j]);
    } else if (i < B8) {
        int j2 = i - B7; int t = j2 >> 3, j = j2 & 7;
        pk[496 + j2] = packh2(wn2[(2 * t) * 8 + j], wn2[(2 * t + 1) * 8 + j]);
    } else if (i < B9) {
        int j2 = i - B8; int t = j2 >> 4, j = j2 & 15;
        pk[528 + j2] = packh2(wn3[(2 * t) * 16 + j], wn3[(2 * t + 1) * 16 + j]);
    } else if (i < B10) {
        int j2 = i - B9; int t = j2 >> 3, j = j2 & 7;
        pk[592 + j2] = packh2(wg2[(2 * t) * 8 + j], wg2[(2 * t + 1) * 8 + j]);
    }
}

// ---------------------------------------------------------------------------
// Kernel A v7: the two s_waitcnt(0) full drains are REMOVED — they waited
// vmcnt(0), i.e. for dfb/fxb global stores to retire, twice per wave, when
// the sFx handoff is same-wave LDS (DS pipe is in-order per wave; compiler
// inserts the result waits). Suspected cause of feats running ~8x roofline.
// Also: 2 tiles per wave (128 pts/block) to amortize weight-fragment loads.
// ---------------------------------------------------------------------------
__global__ __launch_bounds__(256) void feats_kernel(
    const float* __restrict__ df,
    const __bf16* __restrict__ w1Th, const __bf16* __restrict__ w1Tl,
    const float* __restrict__ b1,
    const __bf16* __restrict__ wgT, const float* __restrict__ bg,
    __bf16* __restrict__ fxb, unsigned short* __restrict__ gxh,
    __bf16* __restrict__ dfb, int N)
{
    __shared__ unsigned short sFx[4][16][40];  // per-wave tile, padded rows
    int t = threadIdx.x;
    int wv = t >> 6, ln = t & 63;
    int row = ln & 15, quad = ln >> 4;
    long B0 = (long)blockIdx.x * 128;

    // ---- weight fragments: loaded once, reused for both tiles
    const __bf16* bh = w1Th + (row * 64 + quad * 8);
    const __bf16* bl = w1Tl + (row * 64 + quad * 8);
    bf16x8 bH00 = *(const bf16x8*)(bh);
    bf16x8 bH01 = *(const bf16x8*)(bh + 32);
    bf16x8 bH10 = *(const bf16x8*)(bh + 16 * 64);
    bf16x8 bH11 = *(const bf16x8*)(bh + 16 * 64 + 32);
    bf16x8 bL00 = *(const bf16x8*)(bl);
    bf16x8 bL01 = *(const bf16x8*)(bl + 32);
    bf16x8 bL10 = *(const bf16x8*)(bl + 16 * 64);
    bf16x8 bL11 = *(const bf16x8*)(bl + 16 * 64 + 32);
    bf16x8 b20 = *(const bf16x8*)(wgT + row * 32 + quad * 8);
    bf16x8 b21 = *(const bf16x8*)(wgT + (16 + row) * 32 + quad * 8);
    float bb0 = b1[row], bb1 = b1[16 + row];
    float bgg0 = bg[row], bgg1 = bg[16 + row];

#pragma unroll
    for (int half = 0; half < 2; ++half) {
        long n0 = B0 + half * 64 + wv * 16;
        long n = n0 + row;
        bool ok = n < (long)N;

        // ---- load df row fragment
        const float4* dp = (const float4*)(df + (ok ? n * 64 : 0));
        float4 f00 = dp[quad * 2 + 0], f01 = dp[quad * 2 + 1];
        float4 f10 = dp[8 + quad * 2 + 0], f11 = dp[8 + quad * 2 + 1];
        float s0[8] = {f00.x, f00.y, f00.z, f00.w, f01.x, f01.y, f01.z, f01.w};
        float s1[8] = {f10.x, f10.y, f10.z, f10.w, f11.x, f11.y, f11.z, f11.w};
        bf16x8 aH0, aL0, aH1, aL1;
#pragma unroll
        for (int e = 0; e < 8; e++) {
            __bf16 h = (__bf16)s0[e]; aH0[e] = h; aL0[e] = (__bf16)(s0[e] - (float)h);
            __bf16 g = (__bf16)s1[e]; aH1[e] = g; aL1[e] = (__bf16)(s1[e] - (float)g);
        }
        if (ok) {
            *(bf16x8*)(dfb + n * 64 + quad * 8) = aH0;
            *(bf16x8*)(dfb + n * 64 + 32 + quad * 8) = aH1;
        }

        // ---- GEMM1: fx = leaky(df @ w1 + b1), split-precision MFMA
        f32x4 acc0 = {0.f, 0.f, 0.f, 0.f}, acc1 = {0.f, 0.f, 0.f, 0.f};
        acc0 = __builtin_amdgcn_mfma_f32_16x16x32_bf16(aH0, bH00, acc0, 0, 0, 0);
        acc0 = __builtin_amdgcn_mfma_f32_16x16x32_bf16(aH1, bH01, acc0, 0, 0, 0);
        acc0 = __builtin_amdgcn_mfma_f32_16x16x32_bf16(aL0, bH00, acc0, 0, 0, 0);
        acc0 = __builtin_amdgcn_mfma_f32_16x16x32_bf16(aL1, bH01, acc0, 0, 0, 0);
        acc0 = __builtin_amdgcn_mfma_f32_16x16x32_bf16(aH0, bL00, acc0, 0, 0, 0);
        acc0 = __builtin_amdgcn_mfma_f32_16x16x32_bf16(aH1, bL01, acc0, 0, 0, 0);
        acc1 = __builtin_amdgcn_mfma_f32_16x16x32_bf16(aH0, bH10, acc1, 0, 0, 0);
        acc1 = __builtin_amdgcn_mfma_f32_16x16x32_bf16(aH1, bH11, acc1, 0, 0, 0);
        acc1 = __builtin_amdgcn_mfma_f32_16x16x32_bf16(aL0, bH10, acc1, 0, 0, 0);
        acc1 = __builtin_amdgcn_mfma_f32_16x16x32_bf16(aL1, bH11, acc1, 0, 0, 0);
        acc1 = __builtin_amdgcn_mfma_f32_16x16x32_bf16(aH0, bL10, acc1, 0, 0, 0);
        acc1 = __builtin_amdgcn_mfma_f32_16x16x32_bf16(aH1, bL11, acc1, 0, 0, 0);

        // epilogue -> sFx (bf16 bits); same-wave DS is in-order, no drain
#pragma unroll
        for (int r = 0; r < 4; r++) {
            float x0 = acc0[r] + bb0; x0 = x0 > 0.f ? x0 : 0.1f * x0;
            float x1 = acc1[r] + bb1; x1 = x1 > 0.f ? x1 : 0.1f * x1;
            sFx[wv][quad * 4 + r][row] = __builtin_bit_cast(unsigned short, (__bf16)x0);
            sFx[wv][quad * 4 + r][16 + row] = __builtin_bit_cast(unsigned short, (__bf16)x1);
        }

        // ---- GEMM2: gx = fx @ wg + bg (bf16 MFMA)
        f32x4 g0 = {0.f, 0.f, 0.f, 0.f}, g1 = {0.f, 0.f, 0.f, 0.f};
        {
            bf16x8 a2 = __builtin_bit_cast(bf16x8, *(const ushort8*)(&sFx[wv][row][quad * 8]));
            g0 = __builtin_amdgcn_mfma_f32_16x16x32_bf16(a2, b20, g0, 0, 0, 0);
            g1 = __builtin_amdgcn_mfma_f32_16x16x32_bf16(a2, b21, g1, 0, 0, 0);
        }
        // ---- coalesced fxb store (reads sFx before overwrite)
        {
            int r16 = ln >> 2, seg = ln & 3;
            ushort8 vfx = *(const ushort8*)(&sFx[wv][r16][seg * 8]);
            long nn = n0 + r16;
            if (nn < (long)N) *(ushort8*)((unsigned short*)fxb + nn * 32 + seg * 8) = vfx;
        }
        // ---- overwrite sFx with g-tile (f16 bits), then coalesced gxh store
#pragma unroll
        for (int r = 0; r < 4; r++) {
            sFx[wv][quad * 4 + r][row] = __builtin_bit_cast(unsigned short, (_Float16)(g0[r] + bgg0));
            sFx[wv][quad * 4 + r][16 + row] = __builtin_bit_cast(unsigned short, (_Float16)(g1[r] + bgg1));
        }
        {
            int r16 = ln >> 2, seg = ln & 3;
            ushort8 vg = *(const ushort8*)(&sFx[wv][r16][seg * 8]);
            long nn = n0 + r16;
            if (nn < (long)N) *(ushort8*)(gxh + nn * 32 + seg * 8) = vg;
        }
    }
}

// ---------------------------------------------------------------------------
// Kernel B v7: LDS 30208 -> 26880 (sO aliased into the union's dead-after-
// phase-2 zone; sInd replaced by __shfl) -> 6 blocks/CU. fxb/gxh gathers
// hoisted above the weightnet/pe compute so their latency hides under VALU.
// ---------------------------------------------------------------------------
struct SmemU {
    union {
        struct { __bf16 nfF[16 * 512]; __bf16 w3A[16 * 256]; } a;   // 24576 B
        struct { __bf16 aggB[16][520]; __bf16 sO[16][72]; } b;      // 18944 B
    };
};

__global__ __launch_bounds__(256, 6) void pcf_kernel(
    const float* __restrict__ vi, const int* __restrict__ nei,
    const __bf16* __restrict__ fxb, const unsigned short* __restrict__ gxh,
    const __bf16* __restrict__ dfb,
    const unsigned int* __restrict__ pk,    // packed f16-pair weights
    const float* __restrict__ bpe,
    const float* __restrict__ bg1, const float* __restrict__ bg2,
    const float* __restrict__ bn1, const float* __restrict__ bn2,
    const float* __restrict__ bn3,
    const __bf16* __restrict__ wlinT, const float* __restrict__ blin,
    const __bf16* __restrict__ wu2T, const float* __restrict__ bu2,
    const __bf16* __restrict__ wscT, const float* __restrict__ bsc,
    float* __restrict__ out, int M)
{
    __shared__ SmemU U;
    __shared__ __bf16 sS[16][72];     // shortcut maxpool (lives phase 1->4)

    const unsigned int* wg1P = pk;          // [32t][8j]
    const unsigned int* wpeP = pk + 256;    // [6t][32c]
    const unsigned int* wn1P = pk + 448;    // [6t][8j]
    const unsigned int* wn2P = pk + 496;    // [4t][8j]
    const unsigned int* wn3P = pk + 528;    // [4t][16j]
    const unsigned int* wg2P = pk + 592;    // [4t][8j]

    int t = threadIdx.x;
    int p = t >> 4, q = t & 15;
    long mbase = (long)blockIdx.x * 16;
    long m = mbase + p;
    bool okm = m < (long)M;
    int ind = okm ? nei[m * 16 + q] : 0;

    // ---------------- phase 1 ----------------
    // early gathers: issued now, consumed after the vi-only compute below
    h2 gdh[16];
    {
        const unsigned int* gu = (const unsigned int*)(gxh + (long)ind * 32);
#pragma unroll
        for (int i = 0; i < 16; i++) gdh[i] = __builtin_bit_cast(h2, gu[i]);
    }
    bf16x8 fxr[4];
    {
        const bf16x8* f8 = (const bf16x8*)(fxb + (long)ind * 32);
#pragma unroll
        for (int g = 0; g < 4; g++) fxr[g] = f8[g];
    }
    h2 vh[6];
    {
        const float4* v4 = (const float4*)(vi + (okm ? (m * 16 + q) * 12 : 0));
        float4 a = v4[0], b = v4[1], cc = v4[2];
        vh[0] = (h2){(_Float16)a.x, (_Float16)a.y};
        vh[1] = (h2){(_Float16)a.z, (_Float16)a.w};
        vh[2] = (h2){(_Float16)b.x, (_Float16)b.y};
        vh[3] = (h2){(_Float16)b.z, (_Float16)b.w};
        vh[4] = (h2){(_Float16)cc.x, (_Float16)cc.y};
        vh[5] = (h2){(_Float16)cc.z, (_Float16)cc.w};
    }
    // weightnet chain (dot2, vi-only); write w3 in A-frag layout
    {
        float wa[8];
#pragma unroll
        for (int j = 0; j < 8; j++) {
            float a = bn1[j];
#pragma unroll
            for (int tt2 = 0; tt2 < 6; tt2++)
                a = fdot2(vh[tt2], __builtin_bit_cast(h2, wn1P[tt2 * 8 + j]), a);
            wa[j] = fmaxf(a, 0.f);
        }
        h2 wah[4];
#pragma unroll
        for (int tt2 = 0; tt2 < 4; tt2++)
            wah[tt2] = (h2){(_Float16)wa[2 * tt2], (_Float16)wa[2 * tt2 + 1]};
        float wb[8];
#pragma unroll
        for (int j = 0; j < 8; j++) {
            float a = bn2[j];
#pragma unroll
            for (int tt2 = 0; tt2 < 4; tt2++)
                a = fdot2(wah[tt2], __builtin_bit_cast(h2, wn2P[tt2 * 8 + j]), a);
            wb[j] = fmaxf(a, 0.f);
        }
        h2 wbh[4];
#pragma unroll
        for (int tt2 = 0; tt2 < 4; tt2++)
            wbh[tt2] = (h2){(_Float16)wb[2 * tt2], (_Float16)wb[2 * tt2 + 1]};
        int swz = (p & 3) << 4;
        int kb = (q >> 3) * 128 + (q & 7);
#pragma unroll
        for (int j = 0; j < 16; j++) {
            float a = bn3[j];
#pragma unroll
            for (int tt2 = 0; tt2 < 4; tt2++)
                a = fdot2(wbh[tt2], __builtin_bit_cast(h2, wn3P[tt2 * 16 + j]), a);
            U.a.w3A[p * 256 + ((kb + j * 8) ^ swz)] = (__bf16)fmaxf(a, 0.f);
        }
    }
    // pe = relu(vi@wpe + bpe), packed into pairs
    h2 peh[16];
#pragma unroll
    for (int c2 = 0; c2 < 16; c2++) {
        float a0 = bpe[2 * c2], a1 = bpe[2 * c2 + 1];
#pragma unroll
        for (int tt2 = 0; tt2 < 6; tt2++) {
            a0 = fdot2(vh[tt2], __builtin_bit_cast(h2, wpeP[tt2 * 32 + 2 * c2]), a0);
            a1 = fdot2(vh[tt2], __builtin_bit_cast(h2, wpeP[tt2 * 32 + 2 * c2 + 1]), a1);
        }
        peh[c2] = (h2){(_Float16)fmaxf(a0, 0.f), (_Float16)fmaxf(a1, 0.f)};
    }
    // guidance: s1[j] = sum_t dot2(g2 - rowmax(g2), wg1P[t][j])
    float s1[8];
#pragma unroll
    for (int j = 0; j < 8; j++) s1[j] = bg1[j];
#pragma unroll
    for (int tt2 = 0; tt2 < 32; tt2++) {
        h2 g2 = (tt2 < 16) ? gdh[tt2] : peh[tt2 - 16];
        h2 m2 = rowmax16h(g2);
        h2 sub = g2 - m2;
#pragma unroll
        for (int j = 0; j < 8; j++)
            s1[j] = fdot2(sub, __builtin_bit_cast(h2, wg1P[tt2 * 8 + j]), s1[j]);
    }
    h2 s1h[4];
#pragma unroll
    for (int tt2 = 0; tt2 < 4; tt2++)
        s1h[tt2] = (h2){(_Float16)fmaxf(s1[2 * tt2], 0.f), (_Float16)fmaxf(s1[2 * tt2 + 1], 0.f)};
    float s2[8];
#pragma unroll
    for (int j = 0; j < 8; j++) {
        float a = bg2[j];
#pragma unroll
        for (int tt2 = 0; tt2 < 4; tt2++)
            a = fdot2(s1h[tt2], __builtin_bit_cast(h2, wg2P[tt2 * 8 + j]), a);
        s2[j] = 1.f / (1.f + __expf(-a));
    }
    // nf = gathered fxb * headwise score; write in B-frag layout
    {
        int swz = (p & 3) << 4;
#pragma unroll
        for (int g = 0; g < 4; g++) {
            bf16x8 f = fxr[g];
            float sA = s2[2 * g], sB = s2[2 * g + 1];
#pragma unroll
            for (int e = 0; e < 8; e++) {
                int c = g * 8 + e;
                float val = (float)f[e] * (e < 4 ? sA : sB);
                U.a.nfF[p * 512 + ((((c >> 4) * 256) + (c & 15) * 16 + q) ^ swz)] = (__bf16)val;
            }
        }
    }
    // shortcut maxpool over bf16 df rows (indices via intra-group shuffle)
    {
        float4 mx = make_float4(-1e30f, -1e30f, -1e30f, -1e30f);
#pragma unroll
        for (int kk = 0; kk < 16; kk++) {
            int ik = __shfl(ind, kk, 16);
            bf16x4 d = *(const bf16x4*)(dfb + (long)ik * 64 + q * 4);
            mx.x = fmaxf(mx.x, (float)d[0]); mx.y = fmaxf(mx.y, (float)d[1]);
            mx.z = fmaxf(mx.z, (float)d[2]); mx.w = fmaxf(mx.w, (float)d[3]);
        }
        bf16x4 pkk;
        pkk[0] = (__bf16)mx.x; pkk[1] = (__bf16)mx.y; pkk[2] = (__bf16)mx.z; pkk[3] = (__bf16)mx.w;
        *(bf16x4*)(&sS[p][q * 4]) = pkk;
    }

    // ---------------- phase 2 (MFMA): agg[j][c] per point ----------------
    {
        int wv2 = t >> 6, ln2 = t & 63;
        int col = ln2 & 15, quad = ln2 >> 4;
        bf16x8 z8 = {};
        bf16x4 dpk[4][2];
#pragma unroll
        for (int pp = 0; pp < 4; pp++) {
            int p2 = wv2 * 4 + pp;
            int swz = (p2 & 3) << 4;
            bf16x8 afr = z8, bf0 = z8, bf1 = z8;
            if (quad < 2) {
                afr = *(const bf16x8*)(&U.a.w3A[p2 * 256 + ((quad * 128 + col * 8) ^ swz)]);
                bf0 = *(const bf16x8*)(&U.a.nfF[p2 * 512 + ((col * 16 + quad * 8) ^ swz)]);
                bf1 = *(const bf16x8*)(&U.a.nfF[p2 * 512 + ((256 + col * 16 + quad * 8) ^ swz)]);
            }
            f32x4 ac0 = {0.f, 0.f, 0.f, 0.f}, ac1 = {0.f, 0.f, 0.f, 0.f};
            ac0 = __builtin_amdgcn_mfma_f32_16x16x32_bf16(afr, bf0, ac0, 0, 0, 0);
            ac1 = __builtin_amdgcn_mfma_f32_16x16x32_bf16(afr, bf1, ac1, 0, 0, 0);
#pragma unroll
            for (int r = 0; r < 4; r++) {
                dpk[pp][0][r] = (__bf16)ac0[r];
                dpk[pp][1][r] = (__bf16)ac1[r];
            }
        }
        __syncthreads();          // all frag reads done before aggB overwrite
#pragma unroll
        for (int pp = 0; pp < 4; pp++) {
            int p2 = wv2 * 4 + pp;
            *(bf16x4*)(&U.b.aggB[p2][col * 16 + quad * 4]) = dpk[pp][0];
            *(bf16x4*)(&U.b.aggB[p2][(16 + col) * 16 + quad * 4]) = dpk[pp][1];
        }
    }
    __syncthreads();

    // ---------------- phase 3: out64 = relu(agg @ wlin + blin), MFMA --------
    {
        int wv = t >> 6, ln = t & 63;
        int n = ln & 15, quad = ln >> 4;
        const __bf16* Bp = wlinT + ((wv * 16 + n) * 512 + quad * 8);
        f32x4 acc = {0.f, 0.f, 0.f, 0.f};
#pragma unroll
        for (int kk = 0; kk < 16; kk++) {
            bf16x8 a = *(const bf16x8*)(&U.b.aggB[n][kk * 32 + quad * 8]);
            bf16x8 b = *(const bf16x8*)(Bp + kk * 32);
            acc = __builtin_amdgcn_mfma_f32_16x16x32_bf16(a, b, acc, 0, 0, 0);
        }
        int col = wv * 16 + n;
        float bl = blin[col];
#pragma unroll
        for (int r = 0; r < 4; r++) {
            int row = quad * 4 + r;
            U.b.sO[row][col] = (__bf16)fmaxf(acc[r] + bl, 0.f);
        }
    }
    __syncthreads();

    // ---------------- phase 4: out = leaky(out64@wu2 + sf@wsc + b), MFMA ----
    {
        int wv = t >> 6, ln = t & 63;
        int n = ln & 15, quad = ln >> 4;
        bf16x8 aO0 = *(const bf16x8*)(&U.b.sO[n][quad * 8]);
        bf16x8 aO1 = *(const bf16x8*)(&U.b.sO[n][32 + quad * 8]);
        bf16x8 aS0 = *(const bf16x8*)(&sS[n][quad * 8]);
        bf16x8 aS1 = *(const bf16x8*)(&sS[n][32 + quad * 8]);
#pragma unroll
        for (int tt = 0; tt < 2; tt++) {
            int T = wv * 2 + tt;
            int col = T * 16 + n;
            const __bf16* B1 = wu2T + (col * 64 + quad * 8);
            const __bf16* B2 = wscT + (col * 64 + quad * 8);
            f32x4 acc = {0.f, 0.f, 0.f, 0.f};
            acc = __builtin_amdgcn_mfma_f32_16x16x32_bf16(aO0, *(const bf16x8*)(B1), acc, 0, 0, 0);
            acc = __builtin_amdgcn_mfma_f32_16x16x32_bf16(aO1, *(const bf16x8*)(B1 + 32), acc, 0, 0, 0);
            acc = __builtin_amdgcn_mfma_f32_16x16x32_bf16(aS0, *(const bf16x8*)(B2), acc, 0, 0, 0);
            acc = __builtin_amdgcn_mfma_f32_16x16x32_bf16(aS1, *(const bf16x8*)(B2 + 32), acc, 0, 0, 0);
            float bb = bu2[col] + bsc[col];
#pragma unroll
            for (int r = 0; r < 4; r++) {
                long mm = mbase + quad * 4 + r;
                if (mm < (long)M) {
                    float x = acc[r] + bb;
                    out[mm * 128 + col] = x > 0.f ? x : 0.1f * x;
                }
            }
        }
    }
}

extern "C" void kernel_launch(void* const* d_in, const int* in_sizes, int n_in,
                              void* d_out, int out_size, void* d_ws, size_t ws_size,
                              hipStream_t stream)
{
    const float* dense_feats = (const float*)d_in[1];
    const float* vi    = (const float*)d_in[5];
    const int*   nei   = (const int*)d_in[6];
    const float* w_u1  = (const float*)d_in[7];
    const float* b_u1  = (const float*)d_in[8];
    const float* w_gu  = (const float*)d_in[9];
    const float* b_gu  = (const float*)d_in[10];
    const float* w_pe  = (const float*)d_in[11];
    const float* b_pe  = (const float*)d_in[12];
    const float* w_g1  = (const float*)d_in[13];
    const float* b_g1  = (const float*)d_in[14];
    const float* w_g2  = (const float*)d_in[15];
    const float* b_g2  = (const float*)d_in[16];
    const float* w_wn1 = (const float*)d_in[17];
    const float* b_wn1 = (const float*)d_in[18];
    const float* w_wn2 = (const float*)d_in[19];
    const float* b_wn2 = (const float*)d_in[20];
    const float* w_wn3 = (const float*)d_in[21];
    const float* b_wn3 = (const float*)d_in[22];
    const float* w_lin = (const float*)d_in[23];
    const float* b_lin = (const float*)d_in[24];
    const float* w_u2  = (const float*)d_in[25];
    const float* b_u2  = (const float*)d_in[26];
    const float* w_sc  = (const float*)d_in[27];
    const float* b_sc  = (const float*)d_in[28];

    int N = in_sizes[1] / 64;     // 200000
    int M = in_sizes[6] / 16;     // 100000

    __bf16* fxb  = (__bf16*)d_ws;                        // [N,32] bf16
    unsigned short* gxh = (unsigned short*)(fxb + (size_t)N * 32); // [N,32] f16
    __bf16* dfb  = (__bf16*)(gxh + (size_t)N * 32);      // [N,64] bf16
    __bf16* wlinT = dfb + (size_t)N * 64;                // [64,512]
    __bf16* wu2T  = wlinT + 64 * 512;                    // [128,64]
    __bf16* wscT  = wu2T + 128 * 64;                     // [128,64]
    __bf16* w1Th  = wscT + 128 * 64;                     // [32,64]
    __bf16* w1Tl  = w1Th + 32 * 64;                      // [32,64]
    __bf16* wgT   = w1Tl + 32 * 64;                      // [32,32]
    unsigned int* pk = (unsigned int*)(wgT + 32 * 32);   // 624 packed uints

    const int prep_items = 64 * 512 + 2 * 128 * 64 + 2 * 32 * 64 + 32 * 32 + 624;
    prep_kernel<<<(prep_items + 255) / 256, 256, 0, stream>>>(
        w_lin, w_u2, w_sc, w_u1, w_gu, w_g1, w_pe, w_wn1, w_wn2, w_wn3, w_g2,
        wlinT, wu2T, wscT, w1Th, w1Tl, wgT, pk);

    feats_kernel<<<(N + 127) / 128, 256, 0, stream>>>(
        dense_feats, w1Th, w1Tl, b_u1, wgT, b_gu, fxb, gxh, dfb, N);

    pcf_kernel<<<(M + 15) / 16, 256, 0, stream>>>(
        vi, nei, fxb, gxh, dfb, pk,
        b_pe, b_g1, b_g2, b_wn1, b_wn2, b_wn3,
        wlinT, b_lin, wu2T, b_u2, wscT, b_sc,
        (float*)d_out, M);
}

// Round 10
// 341.228 us; speedup vs baseline: 2.3362x; 1.0270x over previous
//
#include <hip/hip_runtime.h>
#include <math.h>

typedef __attribute__((ext_vector_type(8))) __bf16 bf16x8;
typedef __attribute__((ext_vector_type(4))) __bf16 bf16x4;
typedef __attribute__((ext_vector_type(4))) float f32x4;
typedef __attribute__((ext_vector_type(8))) unsigned short ushort8;
typedef __attribute__((ext_vector_type(2))) _Float16 h2;

__device__ __forceinline__ float fdot2(h2 a, h2 b, float c) {
#if __has_builtin(__builtin_amdgcn_fdot2)
    return __builtin_amdgcn_fdot2(a, b, c, false);
#else
    return c + (float)a[0] * (float)b[0] + (float)a[1] * (float)b[1];
#endif
}

__device__ __forceinline__ h2 h2max(h2 a, h2 b) {
#if __has_builtin(__builtin_elementwise_max)
    return __builtin_elementwise_max(a, b);
#else
    h2 r; r[0] = a[0] > b[0] ? a[0] : b[0]; r[1] = a[1] > b[1] ? a[1] : b[1]; return r;
#endif
}

// packed-pair max over the 16-lane group via DPP row rotations
__device__ __forceinline__ h2 rowmax16h(h2 x) {
    int xi = __builtin_bit_cast(int, x);
    int y;
    y = __builtin_amdgcn_update_dpp(0, xi, 0x128, 0xf, 0xf, true); // ror:8
    x = h2max(x, __builtin_bit_cast(h2, y)); xi = __builtin_bit_cast(int, x);
    y = __builtin_amdgcn_update_dpp(0, xi, 0x124, 0xf, 0xf, true); // ror:4
    x = h2max(x, __builtin_bit_cast(h2, y)); xi = __builtin_bit_cast(int, x);
    y = __builtin_amdgcn_update_dpp(0, xi, 0x122, 0xf, 0xf, true); // ror:2
    x = h2max(x, __builtin_bit_cast(h2, y)); xi = __builtin_bit_cast(int, x);
    y = __builtin_amdgcn_update_dpp(0, xi, 0x121, 0xf, 0xf, true); // ror:1
    x = h2max(x, __builtin_bit_cast(h2, y));
    return x;
}

__device__ __forceinline__ unsigned int packh2(float a, float b) {
    h2 v = { (_Float16)a, (_Float16)b };
    return __builtin_bit_cast(unsigned int, v);
}

// ---------------------------------------------------------------------------
// prep: bf16 transposes for epilogue weights + hi/lo split feats weights +
// f16-pair-packed small-net weights (for v_dot2_f32_f16 chains in pcf).
// ---------------------------------------------------------------------------
__global__ void prep_kernel(const float* __restrict__ wlin,
                            const float* __restrict__ wu2,
                            const float* __restrict__ wsc,
                            const float* __restrict__ w1,
                            const float* __restrict__ wg,
                            const float* __restrict__ wg1,
                            const float* __restrict__ wpe,
                            const float* __restrict__ wn1,
                            const float* __restrict__ wn2,
                            const float* __restrict__ wn3,
                            const float* __restrict__ wg2,
                            __bf16* __restrict__ wlinT,
                            __bf16* __restrict__ wu2T,
                            __bf16* __restrict__ wscT,
                            __bf16* __restrict__ w1Th,
                            __bf16* __restrict__ w1Tl,
                            __bf16* __restrict__ wgT,
                            unsigned int* __restrict__ pk)   // packed block
{
    const int B0 = 64 * 512;              // wlinT
    const int B1 = B0 + 128 * 64;         // wu2T
    const int B2 = B1 + 128 * 64;         // wscT
    const int B3 = B2 + 32 * 64;          // w1Th/l
    const int B4 = B3 + 32 * 32;          // wgT
    const int B5 = B4 + 256;              // wg1P [32t][8j]
    const int B6 = B5 + 192;              // wpeP [6t][32c]
    const int B7 = B6 + 48;               // wn1P [6t][8j]
    const int B8 = B7 + 32;               // wn2P [4t][8j]
    const int B9 = B8 + 64;               // wn3P [4t][16j]
    const int B10 = B9 + 32;              // wg2P [4t][8j]
    int i = blockIdx.x * 256 + threadIdx.x;
    if (i < B0) {
        int l = i >> 9, k = i & 511;
        wlinT[i] = (__bf16)wlin[k * 64 + l];
    } else if (i < B1) {
        int j = i - B0; int co = j >> 6, kk = j & 63;
        wu2T[j] = (__bf16)wu2[kk * 128 + co];
    } else if (i < B2) {
        int j = i - B1; int co = j >> 6, kk = j & 63;
        wscT[j] = (__bf16)wsc[kk * 128 + co];
    } else if (i < B3) {
        int j = i - B2; int c = j >> 6, k = j & 63;
        float v = w1[k * 32 + c];
        __bf16 h = (__bf16)v;
        w1Th[j] = h;
        w1Tl[j] = (__bf16)(v - (float)h);
    } else if (i < B4) {
        int j = i - B3; int c = j >> 5, k = j & 31;
        wgT[j] = (__bf16)wg[k * 32 + c];
    } else if (i < B5) {
        int j2 = i - B4; int t = j2 >> 3, j = j2 & 7;
        pk[j2] = packh2(wg1[(2 * t) * 8 + j], wg1[(2 * t + 1) * 8 + j]);
    } else if (i < B6) {
        int j2 = i - B5; int t = j2 >> 5, c = j2 & 31;
        pk[256 + j2] = packh2(wpe[(2 * t) * 32 + c], wpe[(2 * t + 1) * 32 + c]);
    } else if (i < B7) {
        int j2 = i - B6; int t = j2 >> 3, j = j2 & 7;
        pk[448 + j2] = packh2(wn1[(2 * t) * 8 + j], wn1[(2 * t + 1) * 8 + j]);
    } else if (i < B8) {
        int j2 = i - B7; int t = j2 >> 3, j = j2 & 7;
        pk[496 + j2] = packh2(wn2[(2 * t) * 8 + j], wn2[(2 * t + 1) * 8 + j]);
    } else if (i < B9) {
        int j2 = i - B8; int t = j2 >> 4, j = j2 & 15;
        pk[528 + j2] = packh2(wn3[(2 * t) * 16 + j], wn3[(2 * t + 1) * 16 + j]);
    } else if (i < B10) {
        int j2 = i - B9; int t = j2 >> 3, j = j2 & 7;
        pk[592 + j2] = packh2(wg2[(2 * t) * 8 + j], wg2[(2 * t + 1) * 8 + j]);
    }
}

// ---------------------------------------------------------------------------
// Kernel A v9: round-8 feats (MFMA, no drains, 2 tiles/wave) with fx and gx
// merged into ONE row fgx[n][64] ushorts = [fx bf16[32] | gx f16[32]] =
// exactly one 128B cache line per point. Dtypes UNCHANGED from round 8
// (v8's dtype cluster caused a correctness failure; isolating the layout).
// ---------------------------------------------------------------------------
__global__ __launch_bounds__(256) void feats_kernel(
    const float* __restrict__ df,
    const __bf16* __restrict__ w1Th, const __bf16* __restrict__ w1Tl,
    const float* __restrict__ b1,
    const __bf16* __restrict__ wgT, const float* __restrict__ bg,
    unsigned short* __restrict__ fgx,
    __bf16* __restrict__ dfb, int N)
{
    __shared__ unsigned short sFx[4][16][40];  // per-wave tile, padded rows
    int t = threadIdx.x;
    int wv = t >> 6, ln = t & 63;
    int row = ln & 15, quad = ln >> 4;
    long B0 = (long)blockIdx.x * 128;

    // ---- weight fragments: loaded once, reused for both tiles
    const __bf16* bh = w1Th + (row * 64 + quad * 8);
    const __bf16* bl = w1Tl + (row * 64 + quad * 8);
    bf16x8 bH00 = *(const bf16x8*)(bh);
    bf16x8 bH01 = *(const bf16x8*)(bh + 32);
    bf16x8 bH10 = *(const bf16x8*)(bh + 16 * 64);
    bf16x8 bH11 = *(const bf16x8*)(bh + 16 * 64 + 32);
    bf16x8 bL00 = *(const bf16x8*)(bl);
    bf16x8 bL01 = *(const bf16x8*)(bl + 32);
    bf16x8 bL10 = *(const bf16x8*)(bl + 16 * 64);
    bf16x8 bL11 = *(const bf16x8*)(bl + 16 * 64 + 32);
    bf16x8 b20 = *(const bf16x8*)(wgT + row * 32 + quad * 8);
    bf16x8 b21 = *(const bf16x8*)(wgT + (16 + row) * 32 + quad * 8);
    float bb0 = b1[row], bb1 = b1[16 + row];
    float bgg0 = bg[row], bgg1 = bg[16 + row];

#pragma unroll
    for (int half = 0; half < 2; ++half) {
        long n0 = B0 + half * 64 + wv * 16;
        long n = n0 + row;
        bool ok = n < (long)N;

        // ---- load df row fragment
        const float4* dp = (const float4*)(df + (ok ? n * 64 : 0));
        float4 f00 = dp[quad * 2 + 0], f01 = dp[quad * 2 + 1];
        float4 f10 = dp[8 + quad * 2 + 0], f11 = dp[8 + quad * 2 + 1];
        float s0[8] = {f00.x, f00.y, f00.z, f00.w, f01.x, f01.y, f01.z, f01.w};
        float s1[8] = {f10.x, f10.y, f10.z, f10.w, f11.x, f11.y, f11.z, f11.w};
        bf16x8 aH0, aL0, aH1, aL1;
#pragma unroll
        for (int e = 0; e < 8; e++) {
            __bf16 h = (__bf16)s0[e]; aH0[e] = h; aL0[e] = (__bf16)(s0[e] - (float)h);
            __bf16 g = (__bf16)s1[e]; aH1[e] = g; aL1[e] = (__bf16)(s1[e] - (float)g);
        }
        if (ok) {
            *(bf16x8*)(dfb + n * 64 + quad * 8) = aH0;
            *(bf16x8*)(dfb + n * 64 + 32 + quad * 8) = aH1;
        }

        // ---- GEMM1: fx = leaky(df @ w1 + b1), split-precision MFMA
        f32x4 acc0 = {0.f, 0.f, 0.f, 0.f}, acc1 = {0.f, 0.f, 0.f, 0.f};
        acc0 = __builtin_amdgcn_mfma_f32_16x16x32_bf16(aH0, bH00, acc0, 0, 0, 0);
        acc0 = __builtin_amdgcn_mfma_f32_16x16x32_bf16(aH1, bH01, acc0, 0, 0, 0);
        acc0 = __builtin_amdgcn_mfma_f32_16x16x32_bf16(aL0, bH00, acc0, 0, 0, 0);
        acc0 = __builtin_amdgcn_mfma_f32_16x16x32_bf16(aL1, bH01, acc0, 0, 0, 0);
        acc0 = __builtin_amdgcn_mfma_f32_16x16x32_bf16(aH0, bL00, acc0, 0, 0, 0);
        acc0 = __builtin_amdgcn_mfma_f32_16x16x32_bf16(aH1, bL01, acc0, 0, 0, 0);
        acc1 = __builtin_amdgcn_mfma_f32_16x16x32_bf16(aH0, bH10, acc1, 0, 0, 0);
        acc1 = __builtin_amdgcn_mfma_f32_16x16x32_bf16(aH1, bH11, acc1, 0, 0, 0);
        acc1 = __builtin_amdgcn_mfma_f32_16x16x32_bf16(aL0, bH10, acc1, 0, 0, 0);
        acc1 = __builtin_amdgcn_mfma_f32_16x16x32_bf16(aL1, bH11, acc1, 0, 0, 0);
        acc1 = __builtin_amdgcn_mfma_f32_16x16x32_bf16(aH0, bL10, acc1, 0, 0, 0);
        acc1 = __builtin_amdgcn_mfma_f32_16x16x32_bf16(aH1, bL11, acc1, 0, 0, 0);

        // epilogue -> sFx (bf16 bits); same-wave DS is in-order, no drain
#pragma unroll
        for (int r = 0; r < 4; r++) {
            float x0 = acc0[r] + bb0; x0 = x0 > 0.f ? x0 : 0.1f * x0;
            float x1 = acc1[r] + bb1; x1 = x1 > 0.f ? x1 : 0.1f * x1;
            sFx[wv][quad * 4 + r][row] = __builtin_bit_cast(unsigned short, (__bf16)x0);
            sFx[wv][quad * 4 + r][16 + row] = __builtin_bit_cast(unsigned short, (__bf16)x1);
        }

        // ---- GEMM2: gx = fx @ wg + bg (bf16 MFMA)
        f32x4 g0 = {0.f, 0.f, 0.f, 0.f}, g1 = {0.f, 0.f, 0.f, 0.f};
        {
            bf16x8 a2 = __builtin_bit_cast(bf16x8, *(const ushort8*)(&sFx[wv][row][quad * 8]));
            g0 = __builtin_amdgcn_mfma_f32_16x16x32_bf16(a2, b20, g0, 0, 0, 0);
            g1 = __builtin_amdgcn_mfma_f32_16x16x32_bf16(a2, b21, g1, 0, 0, 0);
        }
        // ---- coalesced fx store into fgx row (reads sFx before overwrite)
        {
            int r16 = ln >> 2, seg = ln & 3;
            ushort8 vfx = *(const ushort8*)(&sFx[wv][r16][seg * 8]);
            long nn = n0 + r16;
            if (nn < (long)N) *(ushort8*)(fgx + nn * 64 + seg * 8) = vfx;
        }
        // ---- overwrite sFx with g-tile (f16 bits), then coalesced gx store
#pragma unroll
        for (int r = 0; r < 4; r++) {
            sFx[wv][quad * 4 + r][row] = __builtin_bit_cast(unsigned short, (_Float16)(g0[r] + bgg0));
            sFx[wv][quad * 4 + r][16 + row] = __builtin_bit_cast(unsigned short, (_Float16)(g1[r] + bgg1));
        }
        {
            int r16 = ln >> 2, seg = ln & 3;
            ushort8 vg = *(const ushort8*)(&sFx[wv][r16][seg * 8]);
            long nn = n0 + r16;
            if (nn < (long)N) *(ushort8*)(fgx + nn * 64 + 32 + seg * 8) = vg;
        }
    }
}

// ---------------------------------------------------------------------------
// Kernel B v9: round-8 pcf (passed) with the fgx single-line gather patched
// in. fx half read as bf16 (identical to round-8 fxb), gx half as f16
// (identical to round-8 gxh). All compute/dtypes unchanged from round 8.
// ---------------------------------------------------------------------------
struct SmemU {
    union {
        struct { __bf16 nfF[16 * 512]; __bf16 w3A[16 * 256]; } a;   // 24576 B
        struct { __bf16 aggB[16][520]; __bf16 sO[16][72]; } b;      // 18944 B
    };
};

__global__ __launch_bounds__(256, 6) void pcf_kernel(
    const float* __restrict__ vi, const int* __restrict__ nei,
    const unsigned short* __restrict__ fgx,
    const __bf16* __restrict__ dfb,
    const unsigned int* __restrict__ pk,    // packed f16-pair weights
    const float* __restrict__ bpe,
    const float* __restrict__ bg1, const float* __restrict__ bg2,
    const float* __restrict__ bn1, const float* __restrict__ bn2,
    const float* __restrict__ bn3,
    const __bf16* __restrict__ wlinT, const float* __restrict__ blin,
    const __bf16* __restrict__ wu2T, const float* __restrict__ bu2,
    const __bf16* __restrict__ wscT, const float* __restrict__ bsc,
    float* __restrict__ out, int M)
{
    __shared__ SmemU U;
    __shared__ __bf16 sS[16][72];     // shortcut maxpool (lives phase 1->4)

    const unsigned int* wg1P = pk;          // [32t][8j]
    const unsigned int* wpeP = pk + 256;    // [6t][32c]
    const unsigned int* wn1P = pk + 448;    // [6t][8j]
    const unsigned int* wn2P = pk + 496;    // [4t][8j]
    const unsigned int* wn3P = pk + 528;    // [4t][16j]
    const unsigned int* wg2P = pk + 592;    // [4t][8j]

    int t = threadIdx.x;
    int p = t >> 4, q = t & 15;
    long mbase = (long)blockIdx.x * 16;
    long m = mbase + p;
    bool okm = m < (long)M;
    int ind = okm ? nei[m * 16 + q] : 0;

    // ---------------- phase 1 ----------------
    // single-line gather: fx (bf16[32]) + gx (f16[32]) in one 128B row
    h2 gdh[16];
    {
        const unsigned int* gu = (const unsigned int*)(fgx + (long)ind * 64 + 32);
#pragma unroll
        for (int i = 0; i < 16; i++) gdh[i] = __builtin_bit_cast(h2, gu[i]);
    }
    bf16x8 fxr[4];
    {
        const bf16x8* f8 = (const bf16x8*)(fgx + (long)ind * 64);
#pragma unroll
        for (int g = 0; g < 4; g++) fxr[g] = f8[g];
    }
    h2 vh[6];
    {
        const float4* v4 = (const float4*)(vi + (okm ? (m * 16 + q) * 12 : 0));
        float4 a = v4[0], b = v4[1], cc = v4[2];
        vh[0] = (h2){(_Float16)a.x, (_Float16)a.y};
        vh[1] = (h2){(_Float16)a.z, (_Float16)a.w};
        vh[2] = (h2){(_Float16)b.x, (_Float16)b.y};
        vh[3] = (h2){(_Float16)b.z, (_Float16)b.w};
        vh[4] = (h2){(_Float16)cc.x, (_Float16)cc.y};
        vh[5] = (h2){(_Float16)cc.z, (_Float16)cc.w};
    }
    // weightnet chain (dot2, vi-only); write w3 in A-frag layout
    {
        float wa[8];
#pragma unroll
        for (int j = 0; j < 8; j++) {
            float a = bn1[j];
#pragma unroll
            for (int tt2 = 0; tt2 < 6; tt2++)
                a = fdot2(vh[tt2], __builtin_bit_cast(h2, wn1P[tt2 * 8 + j]), a);
            wa[j] = fmaxf(a, 0.f);
        }
        h2 wah[4];
#pragma unroll
        for (int tt2 = 0; tt2 < 4; tt2++)
            wah[tt2] = (h2){(_Float16)wa[2 * tt2], (_Float16)wa[2 * tt2 + 1]};
        float wb[8];
#pragma unroll
        for (int j = 0; j < 8; j++) {
            float a = bn2[j];
#pragma unroll
            for (int tt2 = 0; tt2 < 4; tt2++)
                a = fdot2(wah[tt2], __builtin_bit_cast(h2, wn2P[tt2 * 8 + j]), a);
            wb[j] = fmaxf(a, 0.f);
        }
        h2 wbh[4];
#pragma unroll
        for (int tt2 = 0; tt2 < 4; tt2++)
            wbh[tt2] = (h2){(_Float16)wb[2 * tt2], (_Float16)wb[2 * tt2 + 1]};
        int swz = (p & 3) << 4;
        int kb = (q >> 3) * 128 + (q & 7);
#pragma unroll
        for (int j = 0; j < 16; j++) {
            float a = bn3[j];
#pragma unroll
            for (int tt2 = 0; tt2 < 4; tt2++)
                a = fdot2(wbh[tt2], __builtin_bit_cast(h2, wn3P[tt2 * 16 + j]), a);
            U.a.w3A[p * 256 + ((kb + j * 8) ^ swz)] = (__bf16)fmaxf(a, 0.f);
        }
    }
    // pe = relu(vi@wpe + bpe), packed into pairs
    h2 peh[16];
#pragma unroll
    for (int c2 = 0; c2 < 16; c2++) {
        float a0 = bpe[2 * c2], a1 = bpe[2 * c2 + 1];
#pragma unroll
        for (int tt2 = 0; tt2 < 6; tt2++) {
            a0 = fdot2(vh[tt2], __builtin_bit_cast(h2, wpeP[tt2 * 32 + 2 * c2]), a0);
            a1 = fdot2(vh[tt2], __builtin_bit_cast(h2, wpeP[tt2 * 32 + 2 * c2 + 1]), a1);
        }
        peh[c2] = (h2){(_Float16)fmaxf(a0, 0.f), (_Float16)fmaxf(a1, 0.f)};
    }
    // guidance: s1[j] = sum_t dot2(g2 - rowmax(g2), wg1P[t][j])
    float s1[8];
#pragma unroll
    for (int j = 0; j < 8; j++) s1[j] = bg1[j];
#pragma unroll
    for (int tt2 = 0; tt2 < 32; tt2++) {
        h2 g2 = (tt2 < 16) ? gdh[tt2] : peh[tt2 - 16];
        h2 m2 = rowmax16h(g2);
        h2 sub = g2 - m2;
#pragma unroll
        for (int j = 0; j < 8; j++)
            s1[j] = fdot2(sub, __builtin_bit_cast(h2, wg1P[tt2 * 8 + j]), s1[j]);
    }
    h2 s1h[4];
#pragma unroll
    for (int tt2 = 0; tt2 < 4; tt2++)
        s1h[tt2] = (h2){(_Float16)fmaxf(s1[2 * tt2], 0.f), (_Float16)fmaxf(s1[2 * tt2 + 1], 0.f)};
    float s2[8];
#pragma unroll
    for (int j = 0; j < 8; j++) {
        float a = bg2[j];
#pragma unroll
        for (int tt2 = 0; tt2 < 4; tt2++)
            a = fdot2(s1h[tt2], __builtin_bit_cast(h2, wg2P[tt2 * 8 + j]), a);
        s2[j] = 1.f / (1.f + __expf(-a));
    }
    // nf = gathered fx * headwise score; write in B-frag layout (bf16)
    {
        int swz = (p & 3) << 4;
#pragma unroll
        for (int g = 0; g < 4; g++) {
            bf16x8 f = fxr[g];
            float sA = s2[2 * g], sB = s2[2 * g + 1];
#pragma unroll
            for (int e = 0; e < 8; e++) {
                int c = g * 8 + e;
                float val = (float)f[e] * (e < 4 ? sA : sB);
                U.a.nfF[p * 512 + ((((c >> 4) * 256) + (c & 15) * 16 + q) ^ swz)] = (__bf16)val;
            }
        }
    }
    // shortcut maxpool over bf16 df rows (indices via intra-group shuffle)
    {
        float4 mx = make_float4(-1e30f, -1e30f, -1e30f, -1e30f);
#pragma unroll
        for (int kk = 0; kk < 16; kk++) {
            int ik = __shfl(ind, kk, 16);
            bf16x4 d = *(const bf16x4*)(dfb + (long)ik * 64 + q * 4);
            mx.x = fmaxf(mx.x, (float)d[0]); mx.y = fmaxf(mx.y, (float)d[1]);
            mx.z = fmaxf(mx.z, (float)d[2]); mx.w = fmaxf(mx.w, (float)d[3]);
        }
        bf16x4 pkk;
        pkk[0] = (__bf16)mx.x; pkk[1] = (__bf16)mx.y; pkk[2] = (__bf16)mx.z; pkk[3] = (__bf16)mx.w;
        *(bf16x4*)(&sS[p][q * 4]) = pkk;
    }

    // ---------------- phase 2 (MFMA): agg[j][c] per point ----------------
    {
        int wv2 = t >> 6, ln2 = t & 63;
        int col = ln2 & 15, quad = ln2 >> 4;
        bf16x8 z8 = {};
        bf16x4 dpk[4][2];
#pragma unroll
        for (int pp = 0; pp < 4; pp++) {
            int p2 = wv2 * 4 + pp;
            int swz = (p2 & 3) << 4;
            bf16x8 afr = z8, bf0 = z8, bf1 = z8;
            if (quad < 2) {
                afr = *(const bf16x8*)(&U.a.w3A[p2 * 256 + ((quad * 128 + col * 8) ^ swz)]);
                bf0 = *(const bf16x8*)(&U.a.nfF[p2 * 512 + ((col * 16 + quad * 8) ^ swz)]);
                bf1 = *(const bf16x8*)(&U.a.nfF[p2 * 512 + ((256 + col * 16 + quad * 8) ^ swz)]);
            }
            f32x4 ac0 = {0.f, 0.f, 0.f, 0.f}, ac1 = {0.f, 0.f, 0.f, 0.f};
            ac0 = __builtin_amdgcn_mfma_f32_16x16x32_bf16(afr, bf0, ac0, 0, 0, 0);
            ac1 = __builtin_amdgcn_mfma_f32_16x16x32_bf16(afr, bf1, ac1, 0, 0, 0);
#pragma unroll
            for (int r = 0; r < 4; r++) {
                dpk[pp][0][r] = (__bf16)ac0[r];
                dpk[pp][1][r] = (__bf16)ac1[r];
            }
        }
        __syncthreads();          // all frag reads done before aggB overwrite
#pragma unroll
        for (int pp = 0; pp < 4; pp++) {
            int p2 = wv2 * 4 + pp;
            *(bf16x4*)(&U.b.aggB[p2][col * 16 + quad * 4]) = dpk[pp][0];
            *(bf16x4*)(&U.b.aggB[p2][(16 + col) * 16 + quad * 4]) = dpk[pp][1];
        }
    }
    __syncthreads();

    // ---------------- phase 3: out64 = relu(agg @ wlin + blin), MFMA --------
    {
        int wv = t >> 6, ln = t & 63;
        int n = ln & 15, quad = ln >> 4;
        const __bf16* Bp = wlinT + ((wv * 16 + n) * 512 + quad * 8);
        f32x4 acc = {0.f, 0.f, 0.f, 0.f};
#pragma unroll
        for (int kk = 0; kk < 16; kk++) {
            bf16x8 a = *(const bf16x8*)(&U.b.aggB[n][kk * 32 + quad * 8]);
            bf16x8 b = *(const bf16x8*)(Bp + kk * 32);
            acc = __builtin_amdgcn_mfma_f32_16x16x32_bf16(a, b, acc, 0, 0, 0);
        }
        int col = wv * 16 + n;
        float bl = blin[col];
#pragma unroll
        for (int r = 0; r < 4; r++) {
            int row = quad * 4 + r;
            U.b.sO[row][col] = (__bf16)fmaxf(acc[r] + bl, 0.f);
        }
    }
    __syncthreads();

    // ---------------- phase 4: out = leaky(out64@wu2 + sf@wsc + b), MFMA ----
    {
        int wv = t >> 6, ln = t & 63;
        int n = ln & 15, quad = ln >> 4;
        bf16x8 aO0 = *(const bf16x8*)(&U.b.sO[n][quad * 8]);
        bf16x8 aO1 = *(const bf16x8*)(&U.b.sO[n][32 + quad * 8]);
        bf16x8 aS0 = *(const bf16x8*)(&sS[n][quad * 8]);
        bf16x8 aS1 = *(const bf16x8*)(&sS[n][32 + quad * 8]);
#pragma unroll
        for (int tt = 0; tt < 2; tt++) {
            int T = wv * 2 + tt;
            int col = T * 16 + n;
            const __bf16* B1 = wu2T + (col * 64 + quad * 8);
            const __bf16* B2 = wscT + (col * 64 + quad * 8);
            f32x4 acc = {0.f, 0.f, 0.f, 0.f};
            acc = __builtin_amdgcn_mfma_f32_16x16x32_bf16(aO0, *(const bf16x8*)(B1), acc, 0, 0, 0);
            acc = __builtin_amdgcn_mfma_f32_16x16x32_bf16(aO1, *(const bf16x8*)(B1 + 32), acc, 0, 0, 0);
            acc = __builtin_amdgcn_mfma_f32_16x16x32_bf16(aS0, *(const bf16x8*)(B2), acc, 0, 0, 0);
            acc = __builtin_amdgcn_mfma_f32_16x16x32_bf16(aS1, *(const bf16x8*)(B2 + 32), acc, 0, 0, 0);
            float bb = bu2[col] + bsc[col];
#pragma unroll
            for (int r = 0; r < 4; r++) {
                long mm = mbase + quad * 4 + r;
                if (mm < (long)M) {
                    float x = acc[r] + bb;
                    out[mm * 128 + col] = x > 0.f ? x : 0.1f * x;
                }
            }
        }
    }
}

extern "C" void kernel_launch(void* const* d_in, const int* in_sizes, int n_in,
                              void* d_out, int out_size, void* d_ws, size_t ws_size,
                              hipStream_t stream)
{
    const float* dense_feats = (const float*)d_in[1];
    const float* vi    = (const float*)d_in[5];
    const int*   nei   = (const int*)d_in[6];
    const float* w_u1  = (const float*)d_in[7];
    const float* b_u1  = (const float*)d_in[8];
    const float* w_gu  = (const float*)d_in[9];
    const float* b_gu  = (const float*)d_in[10];
    const float* w_pe  = (const float*)d_in[11];
    const float* b_pe  = (const float*)d_in[12];
    const float* w_g1  = (const float*)d_in[13];
    const float* b_g1  = (const float*)d_in[14];
    const float* w_g2  = (const float*)d_in[15];
    const float* b_g2  = (const float*)d_in[16];
    const float* w_wn1 = (const float*)d_in[17];
    const float* b_wn1 = (const float*)d_in[18];
    const float* w_wn2 = (const float*)d_in[19];
    const float* b_wn2 = (const float*)d_in[20];
    const float* w_wn3 = (const float*)d_in[21];
    const float* b_wn3 = (const float*)d_in[22];
    const float* w_lin = (const float*)d_in[23];
    const float* b_lin = (const float*)d_in[24];
    const float* w_u2  = (const float*)d_in[25];
    const float* b_u2  = (const float*)d_in[26];
    const float* w_sc  = (const float*)d_in[27];
    const float* b_sc  = (const float*)d_in[28];

    int N = in_sizes[1] / 64;     // 200000
    int M = in_sizes[6] / 16;     // 100000

    unsigned short* fgx = (unsigned short*)d_ws;         // [N,64]: fx bf16|gx f16
    __bf16* dfb  = (__bf16*)(fgx + (size_t)N * 64);      // [N,64] bf16
    __bf16* wlinT = dfb + (size_t)N * 64;                // [64,512]
    __bf16* wu2T  = wlinT + 64 * 512;                    // [128,64]
    __bf16* wscT  = wu2T + 128 * 64;                     // [128,64]
    __bf16* w1Th  = wscT + 128 * 64;                     // [32,64]
    __bf16* w1Tl  = w1Th + 32 * 64;                      // [32,64]
    __bf16* wgT   = w1Tl + 32 * 64;                      // [32,32]
    unsigned int* pk = (unsigned int*)(wgT + 32 * 32);   // 624 packed uints

    const int prep_items = 64 * 512 + 2 * 128 * 64 + 2 * 32 * 64 + 32 * 32 + 624;
    prep_kernel<<<(prep_items + 255) / 256, 256, 0, stream>>>(
        w_lin, w_u2, w_sc, w_u1, w_gu, w_g1, w_pe, w_wn1, w_wn2, w_wn3, w_g2,
        wlinT, wu2T, wscT, w1Th, w1Tl, wgT, pk);

    feats_kernel<<<(N + 127) / 128, 256, 0, stream>>>(
        dense_feats, w1Th, w1Tl, b_u1, wgT, b_gu, fgx, dfb, N);

    pcf_kernel<<<(M + 15) / 16, 256, 0, stream>>>(
        vi, nei, fgx, dfb, pk,
        b_pe, b_g1, b_g2, b_wn1, b_wn2, b_wn3,
        wlinT, b_lin, wu2T, b_u2, wscT, b_sc,
        (float*)d_out, M);
}